// Round 1
// baseline (606.431 us; speedup 1.0000x reference)
//
#include <hip/hip_runtime.h>
#include <cstddef>

// GCN forward: out = A·(relu(A·(X·W1)+b1))·W2 + b2
// NFEAT=512, NHID=128, NCLS=40 hard-wired in kernels; N,E taken from in_sizes.

// ---------------- GEMM1: C[M,128] = A[M,512] @ B[512,128] (f32) ----------------
__global__ __launch_bounds__(256) void gemm1_kernel(
    const float* __restrict__ A, const float* __restrict__ B,
    float* __restrict__ C, int M)
{
    __shared__ float As[16][72];   // [k][m], padded (72 floats = 288B, 16B-aligned rows)
    __shared__ float Bs[16][128];  // [k][n]

    const int tid  = threadIdx.x;
    const int row0 = blockIdx.x * 64;
    const int tx = tid & 31;       // cols tx*4 .. +3
    const int ty = tid >> 5;       // rows ty*8 .. +7

    const int am = tid >> 2;       // 0..63
    const int ak = (tid & 3) << 2; // 0,4,8,12

    float acc[8][4];
#pragma unroll
    for (int i = 0; i < 8; ++i)
#pragma unroll
        for (int j = 0; j < 4; ++j) acc[i][j] = 0.f;

    for (int k0 = 0; k0 < 512; k0 += 16) {
        const int ar = row0 + am;
        float4 av = make_float4(0.f, 0.f, 0.f, 0.f);
        if (ar < M) av = *(const float4*)(A + (size_t)ar * 512 + k0 + ak);
        const int bk = tid >> 5;   // 0..7
        float4 bv0 = *(const float4*)(B + (size_t)(k0 + bk) * 128 + tx * 4);
        float4 bv1 = *(const float4*)(B + (size_t)(k0 + 8 + bk) * 128 + tx * 4);

        __syncthreads();
        As[ak + 0][am] = av.x; As[ak + 1][am] = av.y;
        As[ak + 2][am] = av.z; As[ak + 3][am] = av.w;
        *(float4*)&Bs[bk][tx * 4]     = bv0;
        *(float4*)&Bs[bk + 8][tx * 4] = bv1;
        __syncthreads();

#pragma unroll
        for (int kk = 0; kk < 16; ++kk) {
            float4 a0 = *(const float4*)&As[kk][ty * 8];
            float4 a1 = *(const float4*)&As[kk][ty * 8 + 4];
            float4 b  = *(const float4*)&Bs[kk][tx * 4];
            const float a[8]  = {a0.x, a0.y, a0.z, a0.w, a1.x, a1.y, a1.z, a1.w};
            const float bb[4] = {b.x, b.y, b.z, b.w};
#pragma unroll
            for (int i = 0; i < 8; ++i)
#pragma unroll
                for (int j = 0; j < 4; ++j)
                    acc[i][j] = fmaf(a[i], bb[j], acc[i][j]);
        }
    }

#pragma unroll
    for (int i = 0; i < 8; ++i) {
        const int gr = row0 + ty * 8 + i;
        if (gr < M) {
            float4 v = make_float4(acc[i][0], acc[i][1], acc[i][2], acc[i][3]);
            *(float4*)(C + (size_t)gr * 128 + tx * 4) = v;
        }
    }
}

// ---------------- init h[i] = b1[i % 128] ----------------
__global__ __launch_bounds__(256) void initH_kernel(float* __restrict__ h,
                                                    const float* __restrict__ b1, int n)
{
    int i = blockIdx.x * 256 + threadIdx.x;
    if (i < n) h[i] = b1[i & 127];
}

// ---------------- scatter1: h[row] += w * xw1[col]  (128 feats, 1 wave/edge) ----------------
__global__ __launch_bounds__(256) void scatter1_kernel(
    const int* __restrict__ row, const int* __restrict__ col,
    const float* __restrict__ w, const float* __restrict__ xw1,
    float* __restrict__ h, int E)
{
    const int wid  = threadIdx.x >> 6;
    const int lane = threadIdx.x & 63;
    const int e = blockIdx.x * 4 + wid;
    if (e >= E) return;
    const int r = row[e], c = col[e];
    const float wt = w[e];
    const float v0 = xw1[(size_t)c * 128 + lane];
    const float v1 = xw1[(size_t)c * 128 + 64 + lane];
    atomicAdd(&h[(size_t)r * 128 + lane], wt * v0);
    atomicAdd(&h[(size_t)r * 128 + 64 + lane], wt * v1);
}

// ---------------- GEMM2: Y[M,40] = relu(H[M,128]) @ W2[128,40] ----------------
__global__ __launch_bounds__(256) void gemm2_kernel(
    const float* __restrict__ H, const float* __restrict__ W2,
    float* __restrict__ Y, int M)
{
    __shared__ float Ws[128][40];   // 20 KB, same layout as W2
    __shared__ float Hs[64][132];   // 33 KB, padded -> 2-way (free) on reads

    const int tid  = threadIdx.x;
    const int row0 = blockIdx.x * 64;

    for (int i = tid; i < 128 * 40; i += 256) ((float*)Ws)[i] = W2[i];

#pragma unroll
    for (int j = 0; j < 8; ++j) {
        int i = tid + j * 256;          // float4 index into 64x128 tile
        int r = i >> 5, c4 = i & 31;
        int gr = row0 + r;
        float4 v = make_float4(0.f, 0.f, 0.f, 0.f);
        if (gr < M) v = *(const float4*)(H + (size_t)gr * 128 + c4 * 4);
        v.x = fmaxf(v.x, 0.f); v.y = fmaxf(v.y, 0.f);
        v.z = fmaxf(v.z, 0.f); v.w = fmaxf(v.w, 0.f);
        Hs[r][c4 * 4 + 0] = v.x; Hs[r][c4 * 4 + 1] = v.y;
        Hs[r][c4 * 4 + 2] = v.z; Hs[r][c4 * 4 + 3] = v.w;
    }
    __syncthreads();

    const int r  = tid >> 2;            // 0..63
    const int c0 = (tid & 3) * 10;      // 0,10,20,30
    float acc[10];
#pragma unroll
    for (int j = 0; j < 10; ++j) acc[j] = 0.f;
    for (int k = 0; k < 128; ++k) {
        float a = Hs[r][k];
#pragma unroll
        for (int j = 0; j < 10; ++j) acc[j] = fmaf(a, Ws[k][c0 + j], acc[j]);
    }
    const int gr = row0 + r;
    if (gr < M) {
#pragma unroll
        for (int j = 0; j < 10; ++j) Y[(size_t)gr * 40 + c0 + j] = acc[j];
    }
}

// ---------------- init out[i] = b2[i % 40] ----------------
__global__ __launch_bounds__(256) void initOut_kernel(float* __restrict__ o,
                                                      const float* __restrict__ b2, int n)
{
    int i = blockIdx.x * 256 + threadIdx.x;
    if (i < n) o[i] = b2[i - (i / 40) * 40];
}

// ---------------- scatter2: out[row] += w * hw2[col]  (40 feats, 6 edges/block) ----------------
__global__ __launch_bounds__(256) void scatter2_kernel(
    const int* __restrict__ row, const int* __restrict__ col,
    const float* __restrict__ w, const float* __restrict__ hw2,
    float* __restrict__ out, int E)
{
    const int t = threadIdx.x;
    if (t >= 240) return;
    const int e = blockIdx.x * 6 + t / 40;
    const int f = t - (t / 40) * 40;
    if (e >= E) return;
    const int r = row[e], c = col[e];
    const float wt = w[e];
    atomicAdd(&out[(size_t)r * 40 + f], wt * hw2[(size_t)c * 40 + f]);
}

extern "C" void kernel_launch(void* const* d_in, const int* in_sizes, int n_in,
                              void* d_out, int out_size, void* d_ws, size_t ws_size,
                              hipStream_t stream)
{
    const float* x  = (const float*)d_in[0];
    const int* erow = (const int*)d_in[1];
    const int* ecol = (const int*)d_in[2];
    const float* ew = (const float*)d_in[3];
    const float* w1 = (const float*)d_in[4];
    const float* b1 = (const float*)d_in[5];
    const float* w2 = (const float*)d_in[6];
    const float* b2 = (const float*)d_in[7];
    float* out = (float*)d_out;

    const int N = in_sizes[0] / 512;   // 50000
    const int E = in_sizes[1];         // 800000

    float* ws  = (float*)d_ws;
    float* xw1 = ws;                     // N*128 floats
    float* h   = ws + (size_t)N * 128;   // N*128 floats
    float* hw2 = ws;                     // N*40 floats (reuses xw1 slot, safe: xw1 dead after scatter1)

    gemm1_kernel<<<(N + 63) / 64, 256, 0, stream>>>(x, w1, xw1, N);
    initH_kernel<<<(N * 128 + 255) / 256, 256, 0, stream>>>(h, b1, N * 128);
    scatter1_kernel<<<(E + 3) / 4, 256, 0, stream>>>(erow, ecol, ew, xw1, h, E);
    gemm2_kernel<<<(N + 63) / 64, 256, 0, stream>>>(h, w2, hw2, N);
    initOut_kernel<<<(N * 40 + 255) / 256, 256, 0, stream>>>(out, b2, N * 40);
    scatter2_kernel<<<(E + 5) / 6, 256, 0, stream>>>(erow, ecol, ew, hw2, out, E);
}

// Round 2
// 350.391 us; speedup vs baseline: 1.7307x; 1.7307x over previous
//
#include <hip/hip_runtime.h>
#include <cstddef>

// GCN forward: out = A·(relu(A·(X·W1)+b1))·W2 + b2
// NFEAT=512, NHID=128, NCLS=40 hard-wired; N,E from in_sizes.
// Strategy: device-built CSR (counting sort by row) -> atomic-free segment-sum SpMMs.

// ---------------- GEMM1: C[M,128] = A[M,512] @ B[512,128] (f32) ----------------
__global__ __launch_bounds__(256) void gemm1_kernel(
    const float* __restrict__ A, const float* __restrict__ B,
    float* __restrict__ C, int M)
{
    __shared__ float As[16][72];
    __shared__ float Bs[16][128];

    const int tid  = threadIdx.x;
    const int row0 = blockIdx.x * 64;
    const int tx = tid & 31;
    const int ty = tid >> 5;

    const int am = tid >> 2;
    const int ak = (tid & 3) << 2;

    float acc[8][4];
#pragma unroll
    for (int i = 0; i < 8; ++i)
#pragma unroll
        for (int j = 0; j < 4; ++j) acc[i][j] = 0.f;

    for (int k0 = 0; k0 < 512; k0 += 16) {
        const int ar = row0 + am;
        float4 av = make_float4(0.f, 0.f, 0.f, 0.f);
        if (ar < M) av = *(const float4*)(A + (size_t)ar * 512 + k0 + ak);
        const int bk = tid >> 5;
        float4 bv0 = *(const float4*)(B + (size_t)(k0 + bk) * 128 + tx * 4);
        float4 bv1 = *(const float4*)(B + (size_t)(k0 + 8 + bk) * 128 + tx * 4);

        __syncthreads();
        As[ak + 0][am] = av.x; As[ak + 1][am] = av.y;
        As[ak + 2][am] = av.z; As[ak + 3][am] = av.w;
        *(float4*)&Bs[bk][tx * 4]     = bv0;
        *(float4*)&Bs[bk + 8][tx * 4] = bv1;
        __syncthreads();

#pragma unroll
        for (int kk = 0; kk < 16; ++kk) {
            float4 a0 = *(const float4*)&As[kk][ty * 8];
            float4 a1 = *(const float4*)&As[kk][ty * 8 + 4];
            float4 b  = *(const float4*)&Bs[kk][tx * 4];
            const float a[8]  = {a0.x, a0.y, a0.z, a0.w, a1.x, a1.y, a1.z, a1.w};
            const float bb[4] = {b.x, b.y, b.z, b.w};
#pragma unroll
            for (int i = 0; i < 8; ++i)
#pragma unroll
                for (int j = 0; j < 4; ++j)
                    acc[i][j] = fmaf(a[i], bb[j], acc[i][j]);
        }
    }

#pragma unroll
    for (int i = 0; i < 8; ++i) {
        const int gr = row0 + ty * 8 + i;
        if (gr < M) {
            float4 v = make_float4(acc[i][0], acc[i][1], acc[i][2], acc[i][3]);
            *(float4*)(C + (size_t)gr * 128 + tx * 4) = v;
        }
    }
}

// ---------------- CSR build ----------------
__global__ __launch_bounds__(256) void zero_kernel(int* __restrict__ p, int n)
{
    int i = blockIdx.x * 256 + threadIdx.x;
    if (i < n) p[i] = 0;
}

__global__ __launch_bounds__(256) void hist_kernel(const int* __restrict__ row,
                                                   int* __restrict__ counts, int E)
{
    int e = blockIdx.x * 256 + threadIdx.x;
    if (e < E) atomicAdd(&counts[row[e]], 1);
}

// per-block exclusive scan; block totals to bsum
__global__ __launch_bounds__(256) void scan1_kernel(const int* __restrict__ counts,
                                                    int* __restrict__ excl,
                                                    int* __restrict__ bsum, int N)
{
    __shared__ int s[256];
    const int t = threadIdx.x;
    const int i = blockIdx.x * 256 + t;
    int v = (i < N) ? counts[i] : 0;
    s[t] = v; __syncthreads();
#pragma unroll
    for (int off = 1; off < 256; off <<= 1) {
        int tmp = (t >= off) ? s[t - off] : 0;
        __syncthreads();
        s[t] += tmp;
        __syncthreads();
    }
    if (i < N) excl[i] = s[t] - v;
    if (t == 255) bsum[blockIdx.x] = s[255];
}

// single-block exclusive scan of block sums (NB <= 256)
__global__ __launch_bounds__(256) void scan2_kernel(int* __restrict__ bsum, int NB)
{
    __shared__ int s[256];
    const int t = threadIdx.x;
    int v = (t < NB) ? bsum[t] : 0;
    s[t] = v; __syncthreads();
#pragma unroll
    for (int off = 1; off < 256; off <<= 1) {
        int tmp = (t >= off) ? s[t - off] : 0;
        __syncthreads();
        s[t] += tmp;
        __syncthreads();
    }
    if (t < NB) bsum[t] = s[t] - v;
}

__global__ __launch_bounds__(256) void scan3_kernel(int* __restrict__ rowptr,
                                                    const int* __restrict__ bsum,
                                                    int* __restrict__ cur, int N, int E)
{
    int i = blockIdx.x * 256 + threadIdx.x;
    if (i < N) {
        int v = rowptr[i] + bsum[blockIdx.x];
        rowptr[i] = v;
        cur[i] = v;
    }
    if (i == 0) rowptr[N] = E;
}

__global__ __launch_bounds__(256) void sortedges_kernel(
    const int* __restrict__ row, const int* __restrict__ col,
    const float* __restrict__ w, int* __restrict__ cur,
    int* __restrict__ scol, float* __restrict__ sw, int E)
{
    int e = blockIdx.x * 256 + threadIdx.x;
    if (e < E) {
        int r = row[e];
        int pos = atomicAdd(&cur[r], 1);
        scol[pos] = col[e];
        sw[pos]   = w[e];
    }
}

// ---------------- segment1: h[r] = b1 + sum_j w_j * xw1[col_j]  (128 feats, wave/row) ----------------
__global__ __launch_bounds__(256) void segment1_kernel(
    const int* __restrict__ rowptr, const int* __restrict__ scol,
    const float* __restrict__ sw, const float* __restrict__ xw1,
    const float* __restrict__ b1, float* __restrict__ h, int N)
{
    const int wid  = threadIdx.x >> 6;
    const int lane = threadIdx.x & 63;
    const int r = blockIdx.x * 4 + wid;
    if (r >= N) return;
    float acc0 = b1[lane];
    float acc1 = b1[64 + lane];
    const int beg = rowptr[r], end = rowptr[r + 1];
    int j = beg;
    for (; j + 1 < end; j += 2) {
        const int   c0 = scol[j],  c1 = scol[j + 1];
        const float w0 = sw[j],    w1 = sw[j + 1];
        const float x00 = xw1[(size_t)c0 * 128 + lane];
        const float x01 = xw1[(size_t)c0 * 128 + 64 + lane];
        const float x10 = xw1[(size_t)c1 * 128 + lane];
        const float x11 = xw1[(size_t)c1 * 128 + 64 + lane];
        acc0 = fmaf(w0, x00, acc0); acc1 = fmaf(w0, x01, acc1);
        acc0 = fmaf(w1, x10, acc0); acc1 = fmaf(w1, x11, acc1);
    }
    if (j < end) {
        const int c = scol[j]; const float wt = sw[j];
        acc0 = fmaf(wt, xw1[(size_t)c * 128 + lane], acc0);
        acc1 = fmaf(wt, xw1[(size_t)c * 128 + 64 + lane], acc1);
    }
    h[(size_t)r * 128 + lane] = acc0;
    h[(size_t)r * 128 + 64 + lane] = acc1;
}

// ---------------- GEMM2: Y[M,40] = relu(H[M,128]) @ W2[128,40] ----------------
__global__ __launch_bounds__(256) void gemm2_kernel(
    const float* __restrict__ H, const float* __restrict__ W2,
    float* __restrict__ Y, int M)
{
    __shared__ float Ws[128][40];
    __shared__ float Hs[64][132];

    const int tid  = threadIdx.x;
    const int row0 = blockIdx.x * 64;

    for (int i = tid; i < 128 * 40; i += 256) ((float*)Ws)[i] = W2[i];

#pragma unroll
    for (int j = 0; j < 8; ++j) {
        int i = tid + j * 256;
        int r = i >> 5, c4 = i & 31;
        int gr = row0 + r;
        float4 v = make_float4(0.f, 0.f, 0.f, 0.f);
        if (gr < M) v = *(const float4*)(H + (size_t)gr * 128 + c4 * 4);
        v.x = fmaxf(v.x, 0.f); v.y = fmaxf(v.y, 0.f);
        v.z = fmaxf(v.z, 0.f); v.w = fmaxf(v.w, 0.f);
        Hs[r][c4 * 4 + 0] = v.x; Hs[r][c4 * 4 + 1] = v.y;
        Hs[r][c4 * 4 + 2] = v.z; Hs[r][c4 * 4 + 3] = v.w;
    }
    __syncthreads();

    const int r  = tid >> 2;
    const int c0 = (tid & 3) * 10;
    float acc[10];
#pragma unroll
    for (int j = 0; j < 10; ++j) acc[j] = 0.f;
    for (int k = 0; k < 128; ++k) {
        float a = Hs[r][k];
#pragma unroll
        for (int j = 0; j < 10; ++j) acc[j] = fmaf(a, Ws[k][c0 + j], acc[j]);
    }
    const int gr = row0 + r;
    if (gr < M) {
#pragma unroll
        for (int j = 0; j < 10; ++j) Y[(size_t)gr * 40 + c0 + j] = acc[j];
    }
}

// ---------------- segment2: out[r] = b2 + sum_j w_j * hw2[col_j]  (40 feats, wave/row) ----------------
__global__ __launch_bounds__(256) void segment2_kernel(
    const int* __restrict__ rowptr, const int* __restrict__ scol,
    const float* __restrict__ sw, const float* __restrict__ hw2,
    const float* __restrict__ b2, float* __restrict__ out, int N)
{
    const int wid  = threadIdx.x >> 6;
    const int lane = threadIdx.x & 63;
    const int r = blockIdx.x * 4 + wid;
    if (r >= N || lane >= 40) return;
    float acc = b2[lane];
    const int beg = rowptr[r], end = rowptr[r + 1];
    int j = beg;
    for (; j + 1 < end; j += 2) {
        const int   c0 = scol[j], c1 = scol[j + 1];
        const float w0 = sw[j],   w1 = sw[j + 1];
        const float v0 = hw2[(size_t)c0 * 40 + lane];
        const float v1 = hw2[(size_t)c1 * 40 + lane];
        acc = fmaf(w0, v0, acc);
        acc = fmaf(w1, v1, acc);
    }
    if (j < end) acc = fmaf(sw[j], hw2[(size_t)scol[j] * 40 + lane], acc);
    out[(size_t)r * 40 + lane] = acc;
}

extern "C" void kernel_launch(void* const* d_in, const int* in_sizes, int n_in,
                              void* d_out, int out_size, void* d_ws, size_t ws_size,
                              hipStream_t stream)
{
    const float* x  = (const float*)d_in[0];
    const int* erow = (const int*)d_in[1];
    const int* ecol = (const int*)d_in[2];
    const float* ew = (const float*)d_in[3];
    const float* w1 = (const float*)d_in[4];
    const float* b1 = (const float*)d_in[5];
    const float* w2 = (const float*)d_in[6];
    const float* b2 = (const float*)d_in[7];
    float* out = (float*)d_out;

    const int N = in_sizes[0] / 512;   // 50000
    const int E = in_sizes[1];         // 800000
    const int NB = (N + 255) / 256;    // 196 (<=256 required by scan2)

    // workspace layout
    float* ws   = (float*)d_ws;
    float* xw1  = ws;                              // N*128 f
    float* h    = xw1 + (size_t)N * 128;           // N*128 f
    int*   rowptr = (int*)(h + (size_t)N * 128);   // N+1
    int*   cur    = rowptr + (N + 1);              // N (counts, then cursors)
    int*   bsum   = cur + N;                       // 256
    int*   scol   = bsum + 256;                    // E
    float* sw     = (float*)(scol + E);            // E
    float* hw2    = xw1;                           // N*40, reuses xw1 (dead after segment1)

    // CSR build
    zero_kernel<<<NB, 256, 0, stream>>>(cur, N);
    hist_kernel<<<(E + 255) / 256, 256, 0, stream>>>(erow, cur, E);
    scan1_kernel<<<NB, 256, 0, stream>>>(cur, rowptr, bsum, N);
    scan2_kernel<<<1, 256, 0, stream>>>(bsum, NB);
    scan3_kernel<<<NB, 256, 0, stream>>>(rowptr, bsum, cur, N, E);
    sortedges_kernel<<<(E + 255) / 256, 256, 0, stream>>>(erow, ecol, ew, cur, scol, sw, E);

    // layer 1
    gemm1_kernel<<<(N + 63) / 64, 256, 0, stream>>>(x, w1, xw1, N);
    segment1_kernel<<<(N + 3) / 4, 256, 0, stream>>>(rowptr, scol, sw, xw1, b1, h, N);

    // layer 2
    gemm2_kernel<<<(N + 63) / 64, 256, 0, stream>>>(h, w2, hw2, N);
    segment2_kernel<<<(N + 3) / 4, 256, 0, stream>>>(rowptr, scol, sw, hw2, b2, out, N);
}

// Round 3
// 279.227 us; speedup vs baseline: 2.1718x; 1.2549x over previous
//
#include <hip/hip_runtime.h>
#include <hip/hip_bf16.h>
#include <cstddef>

// GCN forward: out = A·(relu(A·(X·W1)+b1))·W2 + b2
// NFEAT=512, NHID=128, NCLS=40 hard-wired; N,E from in_sizes.
// CSR (counting sort) -> segment-sum SpMM; GEMM1 via bf16 MFMA; bf16 gather tables.

typedef float f32x4 __attribute__((ext_vector_type(4)));
typedef short bf16x8 __attribute__((ext_vector_type(8)));

static __device__ __forceinline__ short f2bf(float f) {
    __hip_bfloat16 b = __float2bfloat16(f);
    return *reinterpret_cast<short*>(&b);
}
static __device__ __forceinline__ float bflo(unsigned u) {
    union { unsigned i; float f; } v; v.i = u << 16; return v.f;
}
static __device__ __forceinline__ float bfhi(unsigned u) {
    union { unsigned i; float f; } v; v.i = u & 0xFFFF0000u; return v.f;
}

// ---------------- W1 [512][128] f32 -> W1T [128][512] bf16 ----------------
__global__ __launch_bounds__(256) void w1t_kernel(const float* __restrict__ W1,
                                                  short* __restrict__ W1T)
{
    int idx = blockIdx.x * 256 + threadIdx.x;   // 65536 total
    int k = idx >> 7, n = idx & 127;
    W1T[n * 512 + k] = f2bf(W1[idx]);
}

// ---------------- GEMM1: XW1b[M,128](bf16) = X[M,512](f32) @ W1 ----------------
// MFMA 16x16x32 bf16. Block=256 (4 waves); wave w -> rows bid*128 + w*32, all 128 cols.
__global__ __launch_bounds__(256) void gemm1_mfma_kernel(
    const float* __restrict__ X, const short* __restrict__ W1T,
    short* __restrict__ XW1b, int M)
{
    const int tid = threadIdx.x;
    const int w   = tid >> 6;
    const int l   = tid & 63;
    const int l15 = l & 15;
    const int l4  = l >> 4;                 // 0..3
    const int wm0 = blockIdx.x * 128 + w * 32;

    f32x4 acc[2][8];
#pragma unroll
    for (int i = 0; i < 2; ++i)
#pragma unroll
        for (int f = 0; f < 8; ++f) acc[i][f] = (f32x4)0.f;

    const int  ar0 = wm0 + l15;
    const int  ar1 = wm0 + 16 + l15;
    const bool v0 = ar0 < M, v1 = ar1 < M;
    const float* a0p = X + (size_t)ar0 * 512 + l4 * 8;
    const float* a1p = X + (size_t)ar1 * 512 + l4 * 8;
    const short* bp  = W1T + (size_t)l15 * 512 + l4 * 8;

    for (int k0 = 0; k0 < 512; k0 += 32) {
        float4 x00 = make_float4(0.f, 0.f, 0.f, 0.f), x01 = x00, x10 = x00, x11 = x00;
        if (v0) { x00 = *(const float4*)(a0p + k0); x01 = *(const float4*)(a0p + k0 + 4); }
        if (v1) { x10 = *(const float4*)(a1p + k0); x11 = *(const float4*)(a1p + k0 + 4); }
        bf16x8 a0, a1;
        a0[0]=f2bf(x00.x); a0[1]=f2bf(x00.y); a0[2]=f2bf(x00.z); a0[3]=f2bf(x00.w);
        a0[4]=f2bf(x01.x); a0[5]=f2bf(x01.y); a0[6]=f2bf(x01.z); a0[7]=f2bf(x01.w);
        a1[0]=f2bf(x10.x); a1[1]=f2bf(x10.y); a1[2]=f2bf(x10.z); a1[3]=f2bf(x10.w);
        a1[4]=f2bf(x11.x); a1[5]=f2bf(x11.y); a1[6]=f2bf(x11.z); a1[7]=f2bf(x11.w);

        bf16x8 bf[8];
#pragma unroll
        for (int f = 0; f < 8; ++f)
            bf[f] = *(const bf16x8*)(bp + (size_t)f * 16 * 512 + k0);

#pragma unroll
        for (int f = 0; f < 8; ++f) {
            acc[0][f] = __builtin_amdgcn_mfma_f32_16x16x32_bf16(a0, bf[f], acc[0][f], 0, 0, 0);
            acc[1][f] = __builtin_amdgcn_mfma_f32_16x16x32_bf16(a1, bf[f], acc[1][f], 0, 0, 0);
        }
    }

    // D layout: col = lane&15, row = (lane>>4)*4 + reg
#pragma unroll
    for (int i = 0; i < 2; ++i)
#pragma unroll
        for (int r = 0; r < 4; ++r) {
            const int row = wm0 + i * 16 + l4 * 4 + r;
            if (row < M) {
#pragma unroll
                for (int f = 0; f < 8; ++f)
                    XW1b[(size_t)row * 128 + f * 16 + l15] = f2bf(acc[i][f][r]);
            }
        }
}

// ---------------- CSR build ----------------
__global__ __launch_bounds__(256) void zero_kernel(int* __restrict__ p, int n)
{
    int i = blockIdx.x * 256 + threadIdx.x;
    if (i < n) p[i] = 0;
}

__global__ __launch_bounds__(256) void hist_kernel(const int* __restrict__ row,
                                                   int* __restrict__ counts, int E)
{
    int e = blockIdx.x * 256 + threadIdx.x;
    if (e < E) atomicAdd(&counts[row[e]], 1);
}

__global__ __launch_bounds__(256) void scan1_kernel(const int* __restrict__ counts,
                                                    int* __restrict__ excl,
                                                    int* __restrict__ bsum, int N)
{
    __shared__ int s[256];
    const int t = threadIdx.x;
    const int i = blockIdx.x * 256 + t;
    int v = (i < N) ? counts[i] : 0;
    s[t] = v; __syncthreads();
#pragma unroll
    for (int off = 1; off < 256; off <<= 1) {
        int tmp = (t >= off) ? s[t - off] : 0;
        __syncthreads();
        s[t] += tmp;
        __syncthreads();
    }
    if (i < N) excl[i] = s[t] - v;
    if (t == 255) bsum[blockIdx.x] = s[255];
}

__global__ __launch_bounds__(256) void scan2_kernel(int* __restrict__ bsum, int NB)
{
    __shared__ int s[256];
    const int t = threadIdx.x;
    int v = (t < NB) ? bsum[t] : 0;
    s[t] = v; __syncthreads();
#pragma unroll
    for (int off = 1; off < 256; off <<= 1) {
        int tmp = (t >= off) ? s[t - off] : 0;
        __syncthreads();
        s[t] += tmp;
        __syncthreads();
    }
    if (t < NB) bsum[t] = s[t] - v;
}

__global__ __launch_bounds__(256) void scan3_kernel(int* __restrict__ rowptr,
                                                    const int* __restrict__ bsum,
                                                    int* __restrict__ cur, int N, int E)
{
    int i = blockIdx.x * 256 + threadIdx.x;
    if (i < N) {
        int v = rowptr[i] + bsum[blockIdx.x];
        rowptr[i] = v;
        cur[i] = v;
    }
    if (i == 0) rowptr[N] = E;
}

__global__ __launch_bounds__(256) void sortedges_kernel(
    const int* __restrict__ row, const int* __restrict__ col,
    const float* __restrict__ w, int* __restrict__ cur,
    int* __restrict__ scol, float* __restrict__ sw, int E)
{
    int e = blockIdx.x * 256 + threadIdx.x;
    if (e < E) {
        int r = row[e];
        int pos = atomicAdd(&cur[r], 1);
        scol[pos] = col[e];
        sw[pos]   = w[e];
    }
}

// ---------------- segment1: h[r] = b1 + sum_j w_j * xw1b[col_j]  (bf16 gather) ----------------
__global__ __launch_bounds__(256) void segment1_kernel(
    const int* __restrict__ rowptr, const int* __restrict__ scol,
    const float* __restrict__ sw, const unsigned* __restrict__ xw1b,
    const float* __restrict__ b1, float* __restrict__ h, int N)
{
    const int w    = threadIdx.x >> 6;
    const int lane = threadIdx.x & 63;      // feat pair (2*lane, 2*lane+1)
    const int r = blockIdx.x * 4 + w;
    if (r >= N) return;
    float2 bb = *(const float2*)(b1 + 2 * lane);
    float acc0 = bb.x, acc1 = bb.y;
    const int beg = rowptr[r], end = rowptr[r + 1];
    int j = beg;
    for (; j + 1 < end; j += 2) {
        const int   c0 = scol[j],  c1 = scol[j + 1];
        const float w0 = sw[j],    w1 = sw[j + 1];
        const unsigned u0 = xw1b[(size_t)c0 * 64 + lane];
        const unsigned u1 = xw1b[(size_t)c1 * 64 + lane];
        acc0 = fmaf(w0, bflo(u0), acc0); acc1 = fmaf(w0, bfhi(u0), acc1);
        acc0 = fmaf(w1, bflo(u1), acc0); acc1 = fmaf(w1, bfhi(u1), acc1);
    }
    if (j < end) {
        const unsigned u = xw1b[(size_t)scol[j] * 64 + lane];
        const float wt = sw[j];
        acc0 = fmaf(wt, bflo(u), acc0); acc1 = fmaf(wt, bfhi(u), acc1);
    }
    *(float2*)(h + (size_t)r * 128 + 2 * lane) = make_float2(acc0, acc1);
}

// ---------------- GEMM2: Yb[M,40](bf16) = relu(H[M,128]) @ W2[128,40] ----------------
__global__ __launch_bounds__(256) void gemm2_kernel(
    const float* __restrict__ H, const float* __restrict__ W2,
    unsigned* __restrict__ Yb, int M)
{
    __shared__ float Ws[128][40];
    __shared__ float Hs[64][132];

    const int tid  = threadIdx.x;
    const int row0 = blockIdx.x * 64;

    for (int i = tid; i < 128 * 40; i += 256) ((float*)Ws)[i] = W2[i];

#pragma unroll
    for (int j = 0; j < 8; ++j) {
        int i = tid + j * 256;
        int r = i >> 5, c4 = i & 31;
        int gr = row0 + r;
        float4 v = make_float4(0.f, 0.f, 0.f, 0.f);
        if (gr < M) v = *(const float4*)(H + (size_t)gr * 128 + c4 * 4);
        v.x = fmaxf(v.x, 0.f); v.y = fmaxf(v.y, 0.f);
        v.z = fmaxf(v.z, 0.f); v.w = fmaxf(v.w, 0.f);
        Hs[r][c4 * 4 + 0] = v.x; Hs[r][c4 * 4 + 1] = v.y;
        Hs[r][c4 * 4 + 2] = v.z; Hs[r][c4 * 4 + 3] = v.w;
    }
    __syncthreads();

    const int r  = tid >> 2;
    const int c0 = (tid & 3) * 10;
    float acc[10];
#pragma unroll
    for (int j = 0; j < 10; ++j) acc[j] = 0.f;
    for (int k = 0; k < 128; ++k) {
        float a = Hs[r][k];
#pragma unroll
        for (int j = 0; j < 10; ++j) acc[j] = fmaf(a, Ws[k][c0 + j], acc[j]);
    }
    const int gr = row0 + r;
    if (gr < M) {
        unsigned* q = Yb + (size_t)gr * 20 + (c0 >> 1);
#pragma unroll
        for (int j = 0; j < 5; ++j) {
            unsigned lo = (unsigned short)f2bf(acc[2 * j]);
            unsigned hi = (unsigned short)f2bf(acc[2 * j + 1]);
            q[j] = lo | (hi << 16);
        }
    }
}

// ---------------- segment2: out[r] = b2 + sum_j w_j * hw2b[col_j]  (bf16 gather) ----------------
__global__ __launch_bounds__(256) void segment2_kernel(
    const int* __restrict__ rowptr, const int* __restrict__ scol,
    const float* __restrict__ sw, const unsigned* __restrict__ hw2b,
    const float* __restrict__ b2, float* __restrict__ out, int N)
{
    const int w    = threadIdx.x >> 6;
    const int lane = threadIdx.x & 63;      // lanes 0..19: feat pair (2*lane, 2*lane+1)
    const int r = blockIdx.x * 4 + w;
    if (r >= N || lane >= 20) return;
    float2 bb = *(const float2*)(b2 + 2 * lane);
    float acc0 = bb.x, acc1 = bb.y;
    const int beg = rowptr[r], end = rowptr[r + 1];
    int j = beg;
    for (; j + 1 < end; j += 2) {
        const int   c0 = scol[j], c1 = scol[j + 1];
        const float w0 = sw[j],   w1 = sw[j + 1];
        const unsigned u0 = hw2b[(size_t)c0 * 20 + lane];
        const unsigned u1 = hw2b[(size_t)c1 * 20 + lane];
        acc0 = fmaf(w0, bflo(u0), acc0); acc1 = fmaf(w0, bfhi(u0), acc1);
        acc0 = fmaf(w1, bflo(u1), acc0); acc1 = fmaf(w1, bfhi(u1), acc1);
    }
    if (j < end) {
        const unsigned u = hw2b[(size_t)scol[j] * 20 + lane];
        const float wt = sw[j];
        acc0 = fmaf(wt, bflo(u), acc0); acc1 = fmaf(wt, bfhi(u), acc1);
    }
    *(float2*)(out + (size_t)r * 40 + 2 * lane) = make_float2(acc0, acc1);
}

extern "C" void kernel_launch(void* const* d_in, const int* in_sizes, int n_in,
                              void* d_out, int out_size, void* d_ws, size_t ws_size,
                              hipStream_t stream)
{
    const float* x  = (const float*)d_in[0];
    const int* erow = (const int*)d_in[1];
    const int* ecol = (const int*)d_in[2];
    const float* ew = (const float*)d_in[3];
    const float* w1 = (const float*)d_in[4];
    const float* b1 = (const float*)d_in[5];
    const float* w2 = (const float*)d_in[6];
    const float* b2 = (const float*)d_in[7];
    float* out = (float*)d_out;

    const int N = in_sizes[0] / 512;   // 50000
    const int E = in_sizes[1];         // 800000
    const int NB = (N + 255) / 256;    // 196 (<=256 for scan2)

    // workspace layout (w1t first for 16B alignment of bf16x8 loads)
    short* w1t  = (short*)d_ws;                      // 128*512 bf16 (128 KB)
    short* xw1b = w1t + 128 * 512;                   // N*128 bf16
    float* h    = (float*)(xw1b + (size_t)N * 128);  // N*128 f32
    int* rowptr = (int*)(h + (size_t)N * 128);       // N+1
    int* cur    = rowptr + (N + 1);                  // N
    int* bsum   = cur + N;                           // 256
    int* scol   = bsum + 256;                        // E
    float* sw   = (float*)(scol + E);                // E
    short* hw2b = xw1b;                              // N*40 bf16 (reuse, xw1b dead after segment1)

    // CSR build
    zero_kernel<<<NB, 256, 0, stream>>>(cur, N);
    hist_kernel<<<(E + 255) / 256, 256, 0, stream>>>(erow, cur, E);
    scan1_kernel<<<NB, 256, 0, stream>>>(cur, rowptr, bsum, N);
    scan2_kernel<<<1, 256, 0, stream>>>(bsum, NB);
    scan3_kernel<<<NB, 256, 0, stream>>>(rowptr, bsum, cur, N, E);
    sortedges_kernel<<<(E + 255) / 256, 256, 0, stream>>>(erow, ecol, ew, cur, scol, sw, E);

    // layer 1
    w1t_kernel<<<256, 256, 0, stream>>>(w1, w1t);
    gemm1_mfma_kernel<<<(N + 127) / 128, 256, 0, stream>>>(x, w1t, xw1b, N);
    segment1_kernel<<<(N + 3) / 4, 256, 0, stream>>>(rowptr, scol, sw,
                                                     (const unsigned*)xw1b, b1, h, N);

    // layer 2
    gemm2_kernel<<<(N + 63) / 64, 256, 0, stream>>>(h, w2, (unsigned*)hw2b, N);
    segment2_kernel<<<(N + 3) / 4, 256, 0, stream>>>(rowptr, scol, sw,
                                                     (const unsigned*)hw2b, b2, out, N);
}

// Round 4
// 263.992 us; speedup vs baseline: 2.2972x; 1.0577x over previous
//
#include <hip/hip_runtime.h>
#include <hip/hip_bf16.h>
#include <cstddef>

// GCN forward: out = A·(relu(A·(X·W1)+b1))·W2 + b2
// NFEAT=512, NHID=128, NCLS=40 hard-wired; N,E from in_sizes.
// CSR (counting sort) -> segment-sum SpMM; both GEMMs via bf16 MFMA 16x16x32.

typedef float f32x4 __attribute__((ext_vector_type(4)));
typedef short bf16x8 __attribute__((ext_vector_type(8)));

static __device__ __forceinline__ short f2bf(float f) {
    __hip_bfloat16 b = __float2bfloat16(f);
    return *reinterpret_cast<short*>(&b);
}
static __device__ __forceinline__ float bflo(unsigned u) {
    union { unsigned i; float f; } v; v.i = u << 16; return v.f;
}
static __device__ __forceinline__ float bfhi(unsigned u) {
    union { unsigned i; float f; } v; v.i = u & 0xFFFF0000u; return v.f;
}

// ---------------- W1 [512][128] f32 -> W1T [128][512] bf16 ----------------
__global__ __launch_bounds__(256) void w1t_kernel(const float* __restrict__ W1,
                                                  short* __restrict__ W1T)
{
    int idx = blockIdx.x * 256 + threadIdx.x;   // 65536 total
    int k = idx >> 7, n = idx & 127;
    W1T[n * 512 + k] = f2bf(W1[idx]);
}

// ---------------- W2 [128][40] f32 -> W2T [48][128] bf16 (cols 40..47 zero) ----------------
__global__ __launch_bounds__(256) void w2t_kernel(const float* __restrict__ W2,
                                                  short* __restrict__ W2T)
{
    int idx = blockIdx.x * 256 + threadIdx.x;   // 6144 total
    if (idx >= 48 * 128) return;
    int n = idx >> 7, k = idx & 127;
    W2T[idx] = (n < 40) ? f2bf(W2[k * 40 + n]) : (short)0;
}

// ---------------- GEMM1: XW1b[M,128](bf16) = X[M,512](f32) @ W1 ----------------
// Wave = 16 rows x 64 cols. Block 256 = 4 waves -> 32 rows x 128 cols. Grid ceil(M/32).
__global__ __launch_bounds__(256) void gemm1_mfma_kernel(
    const float* __restrict__ X, const short* __restrict__ W1T,
    short* __restrict__ XW1b, int M)
{
    const int tid = threadIdx.x;
    const int w   = tid >> 6;
    const int l   = tid & 63;
    const int l15 = l & 15;
    const int l4  = l >> 4;                       // 0..3
    const int row0 = blockIdx.x * 32 + (w & 1) * 16;
    const int col0 = (w >> 1) * 64;

    f32x4 acc[4];
#pragma unroll
    for (int f = 0; f < 4; ++f) acc[f] = (f32x4)0.f;

    const int  ar = row0 + l15;
    const bool valid = ar < M;
    const float* ap = X + (size_t)ar * 512 + l4 * 8;
    const short* bp = W1T + (size_t)(col0 + l15) * 512 + l4 * 8;

    for (int k0 = 0; k0 < 512; k0 += 32) {
        float4 x0 = make_float4(0.f, 0.f, 0.f, 0.f), x1 = x0;
        if (valid) { x0 = *(const float4*)(ap + k0); x1 = *(const float4*)(ap + k0 + 4); }
        bf16x8 a;
        a[0]=f2bf(x0.x); a[1]=f2bf(x0.y); a[2]=f2bf(x0.z); a[3]=f2bf(x0.w);
        a[4]=f2bf(x1.x); a[5]=f2bf(x1.y); a[6]=f2bf(x1.z); a[7]=f2bf(x1.w);

        bf16x8 bf[4];
#pragma unroll
        for (int f = 0; f < 4; ++f)
            bf[f] = *(const bf16x8*)(bp + (size_t)f * 16 * 512 + k0);

#pragma unroll
        for (int f = 0; f < 4; ++f)
            acc[f] = __builtin_amdgcn_mfma_f32_16x16x32_bf16(a, bf[f], acc[f], 0, 0, 0);
    }

    // D layout: col = lane&15, row = (lane>>4)*4 + reg
#pragma unroll
    for (int r = 0; r < 4; ++r) {
        const int row = row0 + l4 * 4 + r;
        if (row < M) {
#pragma unroll
            for (int f = 0; f < 4; ++f)
                XW1b[(size_t)row * 128 + col0 + f * 16 + l15] = f2bf(acc[f][r]);
        }
    }
}

// ---------------- CSR build ----------------
__global__ __launch_bounds__(256) void zero_kernel(int* __restrict__ p, int n)
{
    int i = blockIdx.x * 256 + threadIdx.x;
    if (i < n) p[i] = 0;
}

__global__ __launch_bounds__(256) void hist_kernel(const int* __restrict__ row,
                                                   int* __restrict__ counts, int E)
{
    int e = blockIdx.x * 256 + threadIdx.x;
    if (e < E) atomicAdd(&counts[row[e]], 1);
}

__global__ __launch_bounds__(256) void scan1_kernel(const int* __restrict__ counts,
                                                    int* __restrict__ excl,
                                                    int* __restrict__ bsum, int N)
{
    __shared__ int s[256];
    const int t = threadIdx.x;
    const int i = blockIdx.x * 256 + t;
    int v = (i < N) ? counts[i] : 0;
    s[t] = v; __syncthreads();
#pragma unroll
    for (int off = 1; off < 256; off <<= 1) {
        int tmp = (t >= off) ? s[t - off] : 0;
        __syncthreads();
        s[t] += tmp;
        __syncthreads();
    }
    if (i < N) excl[i] = s[t] - v;
    if (t == 255) bsum[blockIdx.x] = s[255];
}

__global__ __launch_bounds__(256) void scan2_kernel(int* __restrict__ bsum, int NB)
{
    __shared__ int s[256];
    const int t = threadIdx.x;
    int v = (t < NB) ? bsum[t] : 0;
    s[t] = v; __syncthreads();
#pragma unroll
    for (int off = 1; off < 256; off <<= 1) {
        int tmp = (t >= off) ? s[t - off] : 0;
        __syncthreads();
        s[t] += tmp;
        __syncthreads();
    }
    if (t < NB) bsum[t] = s[t] - v;
}

__global__ __launch_bounds__(256) void scan3_kernel(int* __restrict__ rowptr,
                                                    const int* __restrict__ bsum,
                                                    int* __restrict__ cur, int N, int E)
{
    int i = blockIdx.x * 256 + threadIdx.x;
    if (i < N) {
        int v = rowptr[i] + bsum[blockIdx.x];
        rowptr[i] = v;
        cur[i] = v;
    }
    if (i == 0) rowptr[N] = E;
}

__global__ __launch_bounds__(256) void sortedges_kernel(
    const int* __restrict__ row, const int* __restrict__ col,
    const float* __restrict__ w, int* __restrict__ cur,
    int2* __restrict__ se, int E)
{
    int e = blockIdx.x * 256 + threadIdx.x;
    if (e < E) {
        int r = row[e];
        int pos = atomicAdd(&cur[r], 1);
        se[pos] = make_int2(col[e], __float_as_int(w[e]));
    }
}

// ---------------- segment1: h[r] = b1 + sum_j w_j * xw1b[col_j]  (bf16 gather, x4) ----------------
__global__ __launch_bounds__(256) void segment1_kernel(
    const int* __restrict__ rowptr, const int2* __restrict__ se,
    const unsigned* __restrict__ xw1b, const float* __restrict__ b1,
    float* __restrict__ h, int N)
{
    const int w    = threadIdx.x >> 6;
    const int lane = threadIdx.x & 63;      // feat pair (2*lane, 2*lane+1)
    const int r = blockIdx.x * 4 + w;
    if (r >= N) return;
    float2 bb = *(const float2*)(b1 + 2 * lane);
    float acc0 = bb.x, acc1 = bb.y;
    int j = rowptr[r];
    const int end = rowptr[r + 1];
    for (; j + 3 < end; j += 4) {
        const int2 e0 = se[j], e1 = se[j + 1], e2 = se[j + 2], e3 = se[j + 3];
        const unsigned u0 = xw1b[(size_t)e0.x * 64 + lane];
        const unsigned u1 = xw1b[(size_t)e1.x * 64 + lane];
        const unsigned u2 = xw1b[(size_t)e2.x * 64 + lane];
        const unsigned u3 = xw1b[(size_t)e3.x * 64 + lane];
        const float w0 = __int_as_float(e0.y), w1 = __int_as_float(e1.y);
        const float w2 = __int_as_float(e2.y), w3 = __int_as_float(e3.y);
        acc0 = fmaf(w0, bflo(u0), acc0); acc1 = fmaf(w0, bfhi(u0), acc1);
        acc0 = fmaf(w1, bflo(u1), acc0); acc1 = fmaf(w1, bfhi(u1), acc1);
        acc0 = fmaf(w2, bflo(u2), acc0); acc1 = fmaf(w2, bfhi(u2), acc1);
        acc0 = fmaf(w3, bflo(u3), acc0); acc1 = fmaf(w3, bfhi(u3), acc1);
    }
    for (; j < end; ++j) {
        const int2 e = se[j];
        const unsigned u = xw1b[(size_t)e.x * 64 + lane];
        const float wt = __int_as_float(e.y);
        acc0 = fmaf(wt, bflo(u), acc0); acc1 = fmaf(wt, bfhi(u), acc1);
    }
    *(float2*)(h + (size_t)r * 128 + 2 * lane) = make_float2(acc0, acc1);
}

// ---------------- GEMM2: Yb[M,40](bf16) = relu(H[M,128]) @ W2 via MFMA ----------------
// Wave = 16 rows x 48 cols (40 used). Block 4 waves -> 64 rows. Grid ceil(M/64).
__global__ __launch_bounds__(256) void gemm2_mfma_kernel(
    const float* __restrict__ H, const short* __restrict__ W2T,
    unsigned short* __restrict__ Yb, int M)
{
    const int tid = threadIdx.x;
    const int w   = tid >> 6;
    const int l   = tid & 63;
    const int l15 = l & 15;
    const int l4  = l >> 4;
    const int row0 = blockIdx.x * 64 + w * 16;

    f32x4 acc[3];
#pragma unroll
    for (int f = 0; f < 3; ++f) acc[f] = (f32x4)0.f;

    const int  ar = row0 + l15;
    const bool valid = ar < M;
    const float* hp = H + (size_t)ar * 128 + l4 * 8;
    const short* bp = W2T + (size_t)l15 * 128 + l4 * 8;

#pragma unroll
    for (int k0 = 0; k0 < 128; k0 += 32) {
        float4 x0 = make_float4(0.f, 0.f, 0.f, 0.f), x1 = x0;
        if (valid) { x0 = *(const float4*)(hp + k0); x1 = *(const float4*)(hp + k0 + 4); }
        bf16x8 a;
        a[0]=f2bf(fmaxf(x0.x,0.f)); a[1]=f2bf(fmaxf(x0.y,0.f));
        a[2]=f2bf(fmaxf(x0.z,0.f)); a[3]=f2bf(fmaxf(x0.w,0.f));
        a[4]=f2bf(fmaxf(x1.x,0.f)); a[5]=f2bf(fmaxf(x1.y,0.f));
        a[6]=f2bf(fmaxf(x1.z,0.f)); a[7]=f2bf(fmaxf(x1.w,0.f));

#pragma unroll
        for (int f = 0; f < 3; ++f) {
            bf16x8 b = *(const bf16x8*)(bp + (size_t)f * 16 * 128 + k0);
            acc[f] = __builtin_amdgcn_mfma_f32_16x16x32_bf16(a, b, acc[f], 0, 0, 0);
        }
    }

#pragma unroll
    for (int r = 0; r < 4; ++r) {
        const int row = row0 + l4 * 4 + r;
        if (row < M) {
#pragma unroll
            for (int f = 0; f < 3; ++f) {
                const int col = f * 16 + l15;
                if (col < 40)
                    Yb[(size_t)row * 40 + col] = (unsigned short)f2bf(acc[f][r]);
            }
        }
    }
}

// ---------------- segment2: out[r] = b2 + sum_j w_j * hw2b[col_j]  (bf16 gather, x4) ----------------
__global__ __launch_bounds__(256) void segment2_kernel(
    const int* __restrict__ rowptr, const int2* __restrict__ se,
    const unsigned* __restrict__ hw2b, const float* __restrict__ b2,
    float* __restrict__ out, int N)
{
    const int w    = threadIdx.x >> 6;
    const int lane = threadIdx.x & 63;      // lanes 0..19: feat pair (2*lane, 2*lane+1)
    const int r = blockIdx.x * 4 + w;
    if (r >= N || lane >= 20) return;
    float2 bb = *(const float2*)(b2 + 2 * lane);
    float acc0 = bb.x, acc1 = bb.y;
    int j = rowptr[r];
    const int end = rowptr[r + 1];
    for (; j + 3 < end; j += 4) {
        const int2 e0 = se[j], e1 = se[j + 1], e2 = se[j + 2], e3 = se[j + 3];
        const unsigned u0 = hw2b[(size_t)e0.x * 20 + lane];
        const unsigned u1 = hw2b[(size_t)e1.x * 20 + lane];
        const unsigned u2 = hw2b[(size_t)e2.x * 20 + lane];
        const unsigned u3 = hw2b[(size_t)e3.x * 20 + lane];
        const float w0 = __int_as_float(e0.y), w1 = __int_as_float(e1.y);
        const float w2 = __int_as_float(e2.y), w3 = __int_as_float(e3.y);
        acc0 = fmaf(w0, bflo(u0), acc0); acc1 = fmaf(w0, bfhi(u0), acc1);
        acc0 = fmaf(w1, bflo(u1), acc0); acc1 = fmaf(w1, bfhi(u1), acc1);
        acc0 = fmaf(w2, bflo(u2), acc0); acc1 = fmaf(w2, bfhi(u2), acc1);
        acc0 = fmaf(w3, bflo(u3), acc0); acc1 = fmaf(w3, bfhi(u3), acc1);
    }
    for (; j < end; ++j) {
        const int2 e = se[j];
        const unsigned u = hw2b[(size_t)e.x * 20 + lane];
        const float wt = __int_as_float(e.y);
        acc0 = fmaf(wt, bflo(u), acc0); acc1 = fmaf(wt, bfhi(u), acc1);
    }
    *(float2*)(out + (size_t)r * 40 + 2 * lane) = make_float2(acc0, acc1);
}

extern "C" void kernel_launch(void* const* d_in, const int* in_sizes, int n_in,
                              void* d_out, int out_size, void* d_ws, size_t ws_size,
                              hipStream_t stream)
{
    const float* x  = (const float*)d_in[0];
    const int* erow = (const int*)d_in[1];
    const int* ecol = (const int*)d_in[2];
    const float* ew = (const float*)d_in[3];
    const float* w1 = (const float*)d_in[4];
    const float* b1 = (const float*)d_in[5];
    const float* w2 = (const float*)d_in[6];
    const float* b2 = (const float*)d_in[7];
    float* out = (float*)d_out;

    const int N = in_sizes[0] / 512;   // 50000
    const int E = in_sizes[1];         // 800000
    const int NB = (N + 255) / 256;    // 196 (<=256 for scan2)

    // workspace layout (16B-aligned segments)
    short* w1t  = (short*)d_ws;                      // 128*512 bf16
    short* w2t  = w1t + 65536;                       // 48*128 bf16 (+pad)
    short* xw1b = w2t + 8192;                        // N*128 bf16
    float* h    = (float*)(xw1b + (size_t)N * 128);  // N*128 f32
    int* rowptr = (int*)(h + (size_t)N * 128);       // N+1
    int* cur    = rowptr + (N + 1);                  // N
    int* bsum   = cur + N;                           // 256 (+pad to 8B align)
    int2* se    = (int2*)(bsum + 256 + ((N + 1) & 1)); // E packed edges
    short* hw2b = xw1b;                              // N*40 bf16 (reuse)

    // CSR build
    zero_kernel<<<NB, 256, 0, stream>>>(cur, N);
    hist_kernel<<<(E + 255) / 256, 256, 0, stream>>>(erow, cur, E);
    scan1_kernel<<<NB, 256, 0, stream>>>(cur, rowptr, bsum, N);
    scan2_kernel<<<1, 256, 0, stream>>>(bsum, NB);
    scan3_kernel<<<NB, 256, 0, stream>>>(rowptr, bsum, cur, N, E);
    sortedges_kernel<<<(E + 255) / 256, 256, 0, stream>>>(erow, ecol, ew, cur, se, E);

    // weights
    w1t_kernel<<<256, 256, 0, stream>>>(w1, w1t);
    w2t_kernel<<<24, 256, 0, stream>>>(w2, w2t);

    // layer 1
    gemm1_mfma_kernel<<<(N + 31) / 32, 256, 0, stream>>>(x, w1t, xw1b, N);
    segment1_kernel<<<(N + 3) / 4, 256, 0, stream>>>(rowptr, se,
                                                     (const unsigned*)xw1b, b1, h, N);

    // layer 2
    gemm2_mfma_kernel<<<(N + 63) / 64, 256, 0, stream>>>(h, w2t,
                                                         (unsigned short*)hw2b, N);
    segment2_kernel<<<(N + 3) / 4, 256, 0, stream>>>(rowptr, se,
                                                     (const unsigned*)hw2b, b2, out, N);
}

// Round 5
// 255.582 us; speedup vs baseline: 2.3727x; 1.0329x over previous
//
#include <hip/hip_runtime.h>
#include <hip/hip_bf16.h>
#include <cstddef>

// GCN forward: out = A·(relu(A·(X·W1)+b1))·W2 + b2
// NFEAT=512, NHID=128, NCLS=40 hard-wired; N,E from in_sizes.
// CSR (counting sort) -> segment-sum SpMM; both GEMMs via bf16 MFMA 16x16x32.
// GEMM k-loops are branch-free (clamped rows) + fully unrolled for load pipelining.

typedef float f32x4 __attribute__((ext_vector_type(4)));
typedef short bf16x8 __attribute__((ext_vector_type(8)));

static __device__ __forceinline__ short f2bf(float f) {
    __hip_bfloat16 b = __float2bfloat16(f);
    return *reinterpret_cast<short*>(&b);
}
static __device__ __forceinline__ float bflo(unsigned u) {
    union { unsigned i; float f; } v; v.i = u << 16; return v.f;
}
static __device__ __forceinline__ float bfhi(unsigned u) {
    union { unsigned i; float f; } v; v.i = u & 0xFFFF0000u; return v.f;
}

// ---------------- W1 [512][128] f32 -> W1T [128][512] bf16 ----------------
__global__ __launch_bounds__(256) void w1t_kernel(const float* __restrict__ W1,
                                                  short* __restrict__ W1T)
{
    int idx = blockIdx.x * 256 + threadIdx.x;   // 65536 total
    int k = idx >> 7, n = idx & 127;
    W1T[n * 512 + k] = f2bf(W1[idx]);
}

// ---------------- W2 [128][40] f32 -> W2T [48][128] bf16 (cols 40..47 zero) ----------------
__global__ __launch_bounds__(256) void w2t_kernel(const float* __restrict__ W2,
                                                  short* __restrict__ W2T)
{
    int idx = blockIdx.x * 256 + threadIdx.x;   // 6144 total
    if (idx >= 48 * 128) return;
    int n = idx >> 7, k = idx & 127;
    W2T[idx] = (n < 40) ? f2bf(W2[k * 40 + n]) : (short)0;
}

// ---------------- GEMM1: XW1b[M,128](bf16) = X[M,512](f32) @ W1 ----------------
// Wave = 32 rows x 64 cols (2x4 frags, 8 MFMA/kstep). Block 4 waves = 64 rows x 128 cols.
__global__ __launch_bounds__(256) void gemm1_mfma_kernel(
    const float* __restrict__ X, const short* __restrict__ W1T,
    short* __restrict__ XW1b, int M)
{
    const int tid = threadIdx.x;
    const int w   = tid >> 6;
    const int l   = tid & 63;
    const int l15 = l & 15;
    const int l4  = l >> 4;                        // 0..3
    const int row0 = blockIdx.x * 64 + (w & 1) * 32;
    const int col0 = (w >> 1) * 64;

    f32x4 acc[2][4];
#pragma unroll
    for (int i = 0; i < 2; ++i)
#pragma unroll
        for (int f = 0; f < 4; ++f) acc[i][f] = (f32x4)0.f;

    // clamped rows -> loads unconditional & pipelinable (results discarded at store)
    const int r0 = row0 + l15,      c0 = r0 < M ? r0 : M - 1;
    const int r1 = row0 + 16 + l15, c1 = r1 < M ? r1 : M - 1;
    const float* a0p = X + (size_t)c0 * 512 + l4 * 8;
    const float* a1p = X + (size_t)c1 * 512 + l4 * 8;
    const short* bp  = W1T + (size_t)(col0 + l15) * 512 + l4 * 8;

#pragma unroll
    for (int k0 = 0; k0 < 512; k0 += 32) {
        const float4 x00 = *(const float4*)(a0p + k0);
        const float4 x01 = *(const float4*)(a0p + k0 + 4);
        const float4 x10 = *(const float4*)(a1p + k0);
        const float4 x11 = *(const float4*)(a1p + k0 + 4);

        bf16x8 bf[4];
#pragma unroll
        for (int f = 0; f < 4; ++f)
            bf[f] = *(const bf16x8*)(bp + (size_t)f * 16 * 512 + k0);

        bf16x8 a0, a1;
        a0[0]=f2bf(x00.x); a0[1]=f2bf(x00.y); a0[2]=f2bf(x00.z); a0[3]=f2bf(x00.w);
        a0[4]=f2bf(x01.x); a0[5]=f2bf(x01.y); a0[6]=f2bf(x01.z); a0[7]=f2bf(x01.w);
        a1[0]=f2bf(x10.x); a1[1]=f2bf(x10.y); a1[2]=f2bf(x10.z); a1[3]=f2bf(x10.w);
        a1[4]=f2bf(x11.x); a1[5]=f2bf(x11.y); a1[6]=f2bf(x11.z); a1[7]=f2bf(x11.w);

#pragma unroll
        for (int f = 0; f < 4; ++f) {
            acc[0][f] = __builtin_amdgcn_mfma_f32_16x16x32_bf16(a0, bf[f], acc[0][f], 0, 0, 0);
            acc[1][f] = __builtin_amdgcn_mfma_f32_16x16x32_bf16(a1, bf[f], acc[1][f], 0, 0, 0);
        }
    }

    // D layout: col = lane&15, row = (lane>>4)*4 + reg
#pragma unroll
    for (int i = 0; i < 2; ++i)
#pragma unroll
        for (int r = 0; r < 4; ++r) {
            const int row = row0 + i * 16 + l4 * 4 + r;
            if (row < M) {
#pragma unroll
                for (int f = 0; f < 4; ++f)
                    XW1b[(size_t)row * 128 + col0 + f * 16 + l15] = f2bf(acc[i][f][r]);
            }
        }
}

// ---------------- CSR build ----------------
__global__ __launch_bounds__(256) void zero_kernel(int* __restrict__ p, int n)
{
    int i = blockIdx.x * 256 + threadIdx.x;
    if (i < n) p[i] = 0;
}

__global__ __launch_bounds__(256) void hist_kernel(const int* __restrict__ row,
                                                   int* __restrict__ counts, int E)
{
    int e = blockIdx.x * 256 + threadIdx.x;
    if (e < E) atomicAdd(&counts[row[e]], 1);
}

__global__ __launch_bounds__(256) void scan1_kernel(const int* __restrict__ counts,
                                                    int* __restrict__ excl,
                                                    int* __restrict__ bsum, int N)
{
    __shared__ int s[256];
    const int t = threadIdx.x;
    const int i = blockIdx.x * 256 + t;
    int v = (i < N) ? counts[i] : 0;
    s[t] = v; __syncthreads();
#pragma unroll
    for (int off = 1; off < 256; off <<= 1) {
        int tmp = (t >= off) ? s[t - off] : 0;
        __syncthreads();
        s[t] += tmp;
        __syncthreads();
    }
    if (i < N) excl[i] = s[t] - v;
    if (t == 255) bsum[blockIdx.x] = s[255];
}

__global__ __launch_bounds__(256) void scan2_kernel(int* __restrict__ bsum, int NB)
{
    __shared__ int s[256];
    const int t = threadIdx.x;
    int v = (t < NB) ? bsum[t] : 0;
    s[t] = v; __syncthreads();
#pragma unroll
    for (int off = 1; off < 256; off <<= 1) {
        int tmp = (t >= off) ? s[t - off] : 0;
        __syncthreads();
        s[t] += tmp;
        __syncthreads();
    }
    if (t < NB) bsum[t] = s[t] - v;
}

__global__ __launch_bounds__(256) void scan3_kernel(int* __restrict__ rowptr,
                                                    const int* __restrict__ bsum,
                                                    int* __restrict__ cur, int N, int E)
{
    int i = blockIdx.x * 256 + threadIdx.x;
    if (i < N) {
        int v = rowptr[i] + bsum[blockIdx.x];
        rowptr[i] = v;
        cur[i] = v;
    }
    if (i == 0) rowptr[N] = E;
}

__global__ __launch_bounds__(256) void sortedges_kernel(
    const int* __restrict__ row, const int* __restrict__ col,
    const float* __restrict__ w, int* __restrict__ cur,
    int2* __restrict__ se, int E)
{
    int e = blockIdx.x * 256 + threadIdx.x;
    if (e < E) {
        int r = row[e];
        int pos = atomicAdd(&cur[r], 1);
        se[pos] = make_int2(col[e], __float_as_int(w[e]));
    }
}

// ---------------- segment1: h[r] = b1 + sum_j w_j * xw1b[col_j]  (bf16 gather, x4) ----------------
__global__ __launch_bounds__(256) void segment1_kernel(
    const int* __restrict__ rowptr, const int2* __restrict__ se,
    const unsigned* __restrict__ xw1b, const float* __restrict__ b1,
    float* __restrict__ h, int N)
{
    const int w    = threadIdx.x >> 6;
    const int lane = threadIdx.x & 63;      // feat pair (2*lane, 2*lane+1)
    const int r = blockIdx.x * 4 + w;
    if (r >= N) return;
    float2 bb = *(const float2*)(b1 + 2 * lane);
    float acc0 = bb.x, acc1 = bb.y;
    int j = rowptr[r];
    const int end = rowptr[r + 1];
    for (; j + 3 < end; j += 4) {
        const int2 e0 = se[j], e1 = se[j + 1], e2 = se[j + 2], e3 = se[j + 3];
        const unsigned u0 = xw1b[(size_t)e0.x * 64 + lane];
        const unsigned u1 = xw1b[(size_t)e1.x * 64 + lane];
        const unsigned u2 = xw1b[(size_t)e2.x * 64 + lane];
        const unsigned u3 = xw1b[(size_t)e3.x * 64 + lane];
        const float w0 = __int_as_float(e0.y), w1 = __int_as_float(e1.y);
        const float w2 = __int_as_float(e2.y), w3 = __int_as_float(e3.y);
        acc0 = fmaf(w0, bflo(u0), acc0); acc1 = fmaf(w0, bfhi(u0), acc1);
        acc0 = fmaf(w1, bflo(u1), acc0); acc1 = fmaf(w1, bfhi(u1), acc1);
        acc0 = fmaf(w2, bflo(u2), acc0); acc1 = fmaf(w2, bfhi(u2), acc1);
        acc0 = fmaf(w3, bflo(u3), acc0); acc1 = fmaf(w3, bfhi(u3), acc1);
    }
    for (; j < end; ++j) {
        const int2 e = se[j];
        const unsigned u = xw1b[(size_t)e.x * 64 + lane];
        const float wt = __int_as_float(e.y);
        acc0 = fmaf(wt, bflo(u), acc0); acc1 = fmaf(wt, bfhi(u), acc1);
    }
    *(float2*)(h + (size_t)r * 128 + 2 * lane) = make_float2(acc0, acc1);
}

// ---------------- GEMM2: Yb[M,40](bf16) = relu(H[M,128]) @ W2 via MFMA ----------------
// Wave = 16 rows x 48 cols (40 used). Block 4 waves -> 64 rows. Grid ceil(M/64).
__global__ __launch_bounds__(256) void gemm2_mfma_kernel(
    const float* __restrict__ H, const short* __restrict__ W2T,
    unsigned short* __restrict__ Yb, int M)
{
    const int tid = threadIdx.x;
    const int w   = tid >> 6;
    const int l   = tid & 63;
    const int l15 = l & 15;
    const int l4  = l >> 4;
    const int row0 = blockIdx.x * 64 + w * 16;

    f32x4 acc[3];
#pragma unroll
    for (int f = 0; f < 3; ++f) acc[f] = (f32x4)0.f;

    const int rr = row0 + l15;
    const int cr = rr < M ? rr : M - 1;
    const float* hp = H + (size_t)cr * 128 + l4 * 8;
    const short* bp = W2T + (size_t)l15 * 128 + l4 * 8;

#pragma unroll
    for (int k0 = 0; k0 < 128; k0 += 32) {
        const float4 x0 = *(const float4*)(hp + k0);
        const float4 x1 = *(const float4*)(hp + k0 + 4);
        bf16x8 a;
        a[0]=f2bf(fmaxf(x0.x,0.f)); a[1]=f2bf(fmaxf(x0.y,0.f));
        a[2]=f2bf(fmaxf(x0.z,0.f)); a[3]=f2bf(fmaxf(x0.w,0.f));
        a[4]=f2bf(fmaxf(x1.x,0.f)); a[5]=f2bf(fmaxf(x1.y,0.f));
        a[6]=f2bf(fmaxf(x1.z,0.f)); a[7]=f2bf(fmaxf(x1.w,0.f));

#pragma unroll
        for (int f = 0; f < 3; ++f) {
            bf16x8 b = *(const bf16x8*)(bp + (size_t)f * 16 * 128 + k0);
            acc[f] = __builtin_amdgcn_mfma_f32_16x16x32_bf16(a, b, acc[f], 0, 0, 0);
        }
    }

#pragma unroll
    for (int r = 0; r < 4; ++r) {
        const int row = row0 + l4 * 4 + r;
        if (row < M) {
#pragma unroll
            for (int f = 0; f < 3; ++f) {
                const int col = f * 16 + l15;
                if (col < 40)
                    Yb[(size_t)row * 40 + col] = (unsigned short)f2bf(acc[f][r]);
            }
        }
    }
}

// ---------------- segment2: out[r] = b2 + sum_j w_j * hw2b[col_j]  (bf16 gather, x4) ----------------
__global__ __launch_bounds__(256) void segment2_kernel(
    const int* __restrict__ rowptr, const int2* __restrict__ se,
    const unsigned* __restrict__ hw2b, const float* __restrict__ b2,
    float* __restrict__ out, int N)
{
    const int w    = threadIdx.x >> 6;
    const int lane = threadIdx.x & 63;      // lanes 0..19: feat pair (2*lane, 2*lane+1)
    const int r = blockIdx.x * 4 + w;
    if (r >= N || lane >= 20) return;
    float2 bb = *(const float2*)(b2 + 2 * lane);
    float acc0 = bb.x, acc1 = bb.y;
    int j = rowptr[r];
    const int end = rowptr[r + 1];
    for (; j + 3 < end; j += 4) {
        const int2 e0 = se[j], e1 = se[j + 1], e2 = se[j + 2], e3 = se[j + 3];
        const unsigned u0 = hw2b[(size_t)e0.x * 20 + lane];
        const unsigned u1 = hw2b[(size_t)e1.x * 20 + lane];
        const unsigned u2 = hw2b[(size_t)e2.x * 20 + lane];
        const unsigned u3 = hw2b[(size_t)e3.x * 20 + lane];
        const float w0 = __int_as_float(e0.y), w1 = __int_as_float(e1.y);
        const float w2 = __int_as_float(e2.y), w3 = __int_as_float(e3.y);
        acc0 = fmaf(w0, bflo(u0), acc0); acc1 = fmaf(w0, bfhi(u0), acc1);
        acc0 = fmaf(w1, bflo(u1), acc0); acc1 = fmaf(w1, bfhi(u1), acc1);
        acc0 = fmaf(w2, bflo(u2), acc0); acc1 = fmaf(w2, bfhi(u2), acc1);
        acc0 = fmaf(w3, bflo(u3), acc0); acc1 = fmaf(w3, bfhi(u3), acc1);
    }
    for (; j < end; ++j) {
        const int2 e = se[j];
        const unsigned u = hw2b[(size_t)e.x * 20 + lane];
        const float wt = __int_as_float(e.y);
        acc0 = fmaf(wt, bflo(u), acc0); acc1 = fmaf(wt, bfhi(u), acc1);
    }
    *(float2*)(out + (size_t)r * 40 + 2 * lane) = make_float2(acc0, acc1);
}

extern "C" void kernel_launch(void* const* d_in, const int* in_sizes, int n_in,
                              void* d_out, int out_size, void* d_ws, size_t ws_size,
                              hipStream_t stream)
{
    const float* x  = (const float*)d_in[0];
    const int* erow = (const int*)d_in[1];
    const int* ecol = (const int*)d_in[2];
    const float* ew = (const float*)d_in[3];
    const float* w1 = (const float*)d_in[4];
    const float* b1 = (const float*)d_in[5];
    const float* w2 = (const float*)d_in[6];
    const float* b2 = (const float*)d_in[7];
    float* out = (float*)d_out;

    const int N = in_sizes[0] / 512;   // 50000
    const int E = in_sizes[1];         // 800000
    const int NB = (N + 255) / 256;    // 196 (<=256 for scan2)

    // workspace layout (16B-aligned segments)
    short* w1t  = (short*)d_ws;                      // 128*512 bf16
    short* w2t  = w1t + 65536;                       // 48*128 bf16 (+pad)
    short* xw1b = w2t + 8192;                        // N*128 bf16
    float* h    = (float*)(xw1b + (size_t)N * 128);  // N*128 f32
    int* rowptr = (int*)(h + (size_t)N * 128);       // N+1
    int* cur    = rowptr + (N + 1);                  // N
    int* bsum   = cur + N;                           // 256 (+pad to 8B align)
    int2* se    = (int2*)(bsum + 256 + ((N + 1) & 1)); // E packed edges
    short* hw2b = xw1b;                              // N*40 bf16 (reuse)

    // CSR build
    zero_kernel<<<NB, 256, 0, stream>>>(cur, N);
    hist_kernel<<<(E + 255) / 256, 256, 0, stream>>>(erow, cur, E);
    scan1_kernel<<<NB, 256, 0, stream>>>(cur, rowptr, bsum, N);
    scan2_kernel<<<1, 256, 0, stream>>>(bsum, NB);
    scan3_kernel<<<NB, 256, 0, stream>>>(rowptr, bsum, cur, N, E);
    sortedges_kernel<<<(E + 255) / 256, 256, 0, stream>>>(erow, ecol, ew, cur, se, E);

    // weights
    w1t_kernel<<<256, 256, 0, stream>>>(w1, w1t);
    w2t_kernel<<<24, 256, 0, stream>>>(w2, w2t);

    // layer 1
    gemm1_mfma_kernel<<<(N + 63) / 64, 256, 0, stream>>>(x, w1t, xw1b, N);
    segment1_kernel<<<(N + 3) / 4, 256, 0, stream>>>(rowptr, se,
                                                     (const unsigned*)xw1b, b1, h, N);

    // layer 2
    gemm2_mfma_kernel<<<(N + 63) / 64, 256, 0, stream>>>(h, w2t,
                                                         (unsigned short*)hw2b, N);
    segment2_kernel<<<(N + 3) / 4, 256, 0, stream>>>(rowptr, se,
                                                     (const unsigned*)hw2b, b2, out, N);
}

// Round 6
// 233.638 us; speedup vs baseline: 2.5956x; 1.0939x over previous
//
#include <hip/hip_runtime.h>
#include <hip/hip_bf16.h>
#include <cstddef>

// GCN forward: out = A·(relu(A·(X·W1)+b1))·W2 + b2
// NFEAT=512, NHID=128, NCLS=40 hard-wired; N,E from in_sizes.
// CSR (counting sort) -> segment-sum SpMM; GEMMs via bf16 MFMA 16x16x32.
// gemm1: m97-style global_load_lds double-buffered 2-phase pipeline.

typedef float f32x4 __attribute__((ext_vector_type(4)));
typedef short bf16x8 __attribute__((ext_vector_type(8)));

static __device__ __forceinline__ short f2bf(float f) {
    __hip_bfloat16 b = __float2bfloat16(f);
    return *reinterpret_cast<short*>(&b);
}
static __device__ __forceinline__ float bflo(unsigned u) {
    union { unsigned i; float f; } v; v.i = u << 16; return v.f;
}
static __device__ __forceinline__ float bfhi(unsigned u) {
    union { unsigned i; float f; } v; v.i = u & 0xFFFF0000u; return v.f;
}

typedef const __attribute__((address_space(1))) void* gas_ptr;
typedef __attribute__((address_space(3))) void* las_ptr;
static __device__ __forceinline__ void gload16(const void* g, void* l) {
    // async global->LDS, 16B per lane; LDS dest = uniform base + lane*16
    __builtin_amdgcn_global_load_lds((gas_ptr)g, (las_ptr)l, 16, 0, 0);
}

// ---------------- W1 [512][128] f32 -> W1T [128][512] bf16 ----------------
__global__ __launch_bounds__(256) void w1t_kernel(const float* __restrict__ W1,
                                                  short* __restrict__ W1T)
{
    int idx = blockIdx.x * 256 + threadIdx.x;   // 65536 total
    int k = idx >> 7, n = idx & 127;
    W1T[n * 512 + k] = f2bf(W1[idx]);
}

// ---------------- W2 [128][40] f32 -> W2T [48][128] bf16 (cols 40..47 zero) ----------------
__global__ __launch_bounds__(256) void w2t_kernel(const float* __restrict__ W2,
                                                  short* __restrict__ W2T)
{
    int idx = blockIdx.x * 256 + threadIdx.x;   // 6144 total
    if (idx >= 48 * 128) return;
    int n = idx >> 7, k = idx & 127;
    W2T[idx] = (n < 40) ? f2bf(W2[k * 40 + n]) : (short)0;
}

// ---------------- GEMM1: XW1b[M,128](bf16) = X[M,512](f32) @ W1 ----------------
// Block 256thr/4 waves, out-tile 64r x 128c; wave = 32r x 64c (2x4 frags).
// K-tiles of 64; As[2][64][64] f32 + Bs[2][128][64] bf16 = 64KB LDS (2 blocks/CU).
// 2-phase: stage(kt+1) -> compute(kt) -> barrier.
__global__ __launch_bounds__(256) void gemm1_mfma_kernel(
    const float* __restrict__ X, const short* __restrict__ W1T,
    short* __restrict__ XW1b, int M)
{
    __shared__ float As[2][64][64];    // 32 KB
    __shared__ short Bs[2][128][64];   // 32 KB

    const int tid = threadIdx.x;
    const int w   = tid >> 6;
    const int l   = tid & 63;
    const int l15 = l & 15;
    const int l4  = l >> 4;
    const int row0 = blockIdx.x * 64;
    const int rb   = (w & 1) * 32;     // wave's row offset in tile
    const int cb   = (w >> 1) * 64;    // wave's col offset in tile

    f32x4 acc[2][4];
#pragma unroll
    for (int i = 0; i < 2; ++i)
#pragma unroll
        for (int f = 0; f < 4; ++f) acc[i][f] = (f32x4)0.f;

    // ---- staging: per wave 4 issues A (4KB each) + 4 issues B ----
    auto STAGE = [&](int b, int kt) {
        const int kof = kt * 64;
#pragma unroll
        for (int i = 0; i < 4; ++i) {
            // LDS linear bytes [i*4096 + w*1024 + lane*16): row r=i*16+w*4+(l>>4), col 4*(l&15)
            int gr = row0 + i * 16 + w * 4 + (l >> 4);
            gr = gr < M ? gr : M - 1;
            const float* src = X + (size_t)gr * 512 + kof + 4 * (l & 15);
            void* dst = (char*)&As[b][0][0] + i * 4096 + w * 1024;
            gload16(src, dst);
        }
#pragma unroll
        for (int i = 0; i < 4; ++i) {
            // LDS linear: n = i*32 + w*8 + (l>>3), k = 8*(l&7)
            const int n = i * 32 + w * 8 + (l >> 3);
            const short* src = W1T + (size_t)n * 512 + kof + 8 * (l & 7);
            void* dst = (char*)&Bs[b][0][0] + i * 4096 + w * 1024;
            gload16(src, dst);
        }
    };

    auto COMPUTE = [&](int b) {
#pragma unroll
        for (int kk = 0; kk < 2; ++kk) {
            bf16x8 bfr[4];
#pragma unroll
            for (int f = 0; f < 4; ++f)
                bfr[f] = *(const bf16x8*)&Bs[b][cb + f * 16 + l15][kk * 32 + l4 * 8];
            bf16x8 a[2];
#pragma unroll
            for (int i = 0; i < 2; ++i) {
                const float* pa = &As[b][rb + i * 16 + l15][kk * 32 + l4 * 8];
                const float4 x0 = *(const float4*)(pa);
                const float4 x1 = *(const float4*)(pa + 4);
                a[i][0]=f2bf(x0.x); a[i][1]=f2bf(x0.y); a[i][2]=f2bf(x0.z); a[i][3]=f2bf(x0.w);
                a[i][4]=f2bf(x1.x); a[i][5]=f2bf(x1.y); a[i][6]=f2bf(x1.z); a[i][7]=f2bf(x1.w);
            }
#pragma unroll
            for (int f = 0; f < 4; ++f) {
                acc[0][f] = __builtin_amdgcn_mfma_f32_16x16x32_bf16(a[0], bfr[f], acc[0][f], 0, 0, 0);
                acc[1][f] = __builtin_amdgcn_mfma_f32_16x16x32_bf16(a[1], bfr[f], acc[1][f], 0, 0, 0);
            }
        }
    };

    STAGE(0, 0);
    __syncthreads();
#pragma unroll
    for (int kt = 0; kt < 8; ++kt) {
        if (kt + 1 < 8) STAGE((kt + 1) & 1, kt + 1);   // async prefetch next tile
        COMPUTE(kt & 1);                                // MFMA current tile
        __syncthreads();                                // drains vmcnt+lgkmcnt
    }

    // D layout: col = lane&15, row = (lane>>4)*4 + reg
#pragma unroll
    for (int i = 0; i < 2; ++i)
#pragma unroll
        for (int r = 0; r < 4; ++r) {
            const int row = row0 + rb + i * 16 + l4 * 4 + r;
            if (row < M) {
#pragma unroll
                for (int f = 0; f < 4; ++f)
                    XW1b[(size_t)row * 128 + cb + f * 16 + l15] = f2bf(acc[i][f][r]);
            }
        }
}

// ---------------- CSR build ----------------
__global__ __launch_bounds__(256) void zero_kernel(int* __restrict__ p, int n)
{
    int i = blockIdx.x * 256 + threadIdx.x;
    if (i < n) p[i] = 0;
}

__global__ __launch_bounds__(256) void hist_kernel(const int* __restrict__ row,
                                                   int* __restrict__ counts, int E)
{
    int e = blockIdx.x * 256 + threadIdx.x;
    if (e < E) atomicAdd(&counts[row[e]], 1);
}

__global__ __launch_bounds__(256) void scan1_kernel(const int* __restrict__ counts,
                                                    int* __restrict__ excl,
                                                    int* __restrict__ bsum, int N)
{
    __shared__ int s[256];
    const int t = threadIdx.x;
    const int i = blockIdx.x * 256 + t;
    int v = (i < N) ? counts[i] : 0;
    s[t] = v; __syncthreads();
#pragma unroll
    for (int off = 1; off < 256; off <<= 1) {
        int tmp = (t >= off) ? s[t - off] : 0;
        __syncthreads();
        s[t] += tmp;
        __syncthreads();
    }
    if (i < N) excl[i] = s[t] - v;
    if (t == 255) bsum[blockIdx.x] = s[255];
}

__global__ __launch_bounds__(256) void scan2_kernel(int* __restrict__ bsum, int NB)
{
    __shared__ int s[256];
    const int t = threadIdx.x;
    int v = (t < NB) ? bsum[t] : 0;
    s[t] = v; __syncthreads();
#pragma unroll
    for (int off = 1; off < 256; off <<= 1) {
        int tmp = (t >= off) ? s[t - off] : 0;
        __syncthreads();
        s[t] += tmp;
        __syncthreads();
    }
    if (t < NB) bsum[t] = s[t] - v;
}

__global__ __launch_bounds__(256) void scan3_kernel(int* __restrict__ rowptr,
                                                    const int* __restrict__ bsum,
                                                    int* __restrict__ cur, int N, int E)
{
    int i = blockIdx.x * 256 + threadIdx.x;
    if (i < N) {
        int v = rowptr[i] + bsum[blockIdx.x];
        rowptr[i] = v;
        cur[i] = v;
    }
    if (i == 0) rowptr[N] = E;
}

__global__ __launch_bounds__(256) void sortedges_kernel(
    const int* __restrict__ row, const int* __restrict__ col,
    const float* __restrict__ w, int* __restrict__ cur,
    int2* __restrict__ se, int E)
{
    int e = blockIdx.x * 256 + threadIdx.x;
    if (e < E) {
        int r = row[e];
        int pos = atomicAdd(&cur[r], 1);
        se[pos] = make_int2(col[e], __float_as_int(w[e]));
    }
}

// ---------------- segment1: h[r] = b1 + sum_j w_j * xw1b[col_j]  (bf16 gather, x4) ----------------
__global__ __launch_bounds__(256) void segment1_kernel(
    const int* __restrict__ rowptr, const int2* __restrict__ se,
    const unsigned* __restrict__ xw1b, const float* __restrict__ b1,
    float* __restrict__ h, int N)
{
    const int w    = threadIdx.x >> 6;
    const int lane = threadIdx.x & 63;      // feat pair (2*lane, 2*lane+1)
    const int r = blockIdx.x * 4 + w;
    if (r >= N) return;
    float2 bb = *(const float2*)(b1 + 2 * lane);
    float acc0 = bb.x, acc1 = bb.y;
    int j = rowptr[r];
    const int end = rowptr[r + 1];
    for (; j + 3 < end; j += 4) {
        const int2 e0 = se[j], e1 = se[j + 1], e2 = se[j + 2], e3 = se[j + 3];
        const unsigned u0 = xw1b[(size_t)e0.x * 64 + lane];
        const unsigned u1 = xw1b[(size_t)e1.x * 64 + lane];
        const unsigned u2 = xw1b[(size_t)e2.x * 64 + lane];
        const unsigned u3 = xw1b[(size_t)e3.x * 64 + lane];
        const float w0 = __int_as_float(e0.y), w1 = __int_as_float(e1.y);
        const float w2 = __int_as_float(e2.y), w3 = __int_as_float(e3.y);
        acc0 = fmaf(w0, bflo(u0), acc0); acc1 = fmaf(w0, bfhi(u0), acc1);
        acc0 = fmaf(w1, bflo(u1), acc0); acc1 = fmaf(w1, bfhi(u1), acc1);
        acc0 = fmaf(w2, bflo(u2), acc0); acc1 = fmaf(w2, bfhi(u2), acc1);
        acc0 = fmaf(w3, bflo(u3), acc0); acc1 = fmaf(w3, bfhi(u3), acc1);
    }
    for (; j < end; ++j) {
        const int2 e = se[j];
        const unsigned u = xw1b[(size_t)e.x * 64 + lane];
        const float wt = __int_as_float(e.y);
        acc0 = fmaf(wt, bflo(u), acc0); acc1 = fmaf(wt, bfhi(u), acc1);
    }
    *(float2*)(h + (size_t)r * 128 + 2 * lane) = make_float2(acc0, acc1);
}

// ---------------- GEMM2: Yb[M,40](bf16) = relu(H[M,128]) @ W2 via MFMA ----------------
__global__ __launch_bounds__(256) void gemm2_mfma_kernel(
    const float* __restrict__ H, const short* __restrict__ W2T,
    unsigned short* __restrict__ Yb, int M)
{
    const int tid = threadIdx.x;
    const int w   = tid >> 6;
    const int l   = tid & 63;
    const int l15 = l & 15;
    const int l4  = l >> 4;
    const int row0 = blockIdx.x * 64 + w * 16;

    f32x4 acc[3];
#pragma unroll
    for (int f = 0; f < 3; ++f) acc[f] = (f32x4)0.f;

    const int rr = row0 + l15;
    const int cr = rr < M ? rr : M - 1;
    const float* hp = H + (size_t)cr * 128 + l4 * 8;
    const short* bp = W2T + (size_t)l15 * 128 + l4 * 8;

#pragma unroll
    for (int k0 = 0; k0 < 128; k0 += 32) {
        const float4 x0 = *(const float4*)(hp + k0);
        const float4 x1 = *(const float4*)(hp + k0 + 4);
        bf16x8 a;
        a[0]=f2bf(fmaxf(x0.x,0.f)); a[1]=f2bf(fmaxf(x0.y,0.f));
        a[2]=f2bf(fmaxf(x0.z,0.f)); a[3]=f2bf(fmaxf(x0.w,0.f));
        a[4]=f2bf(fmaxf(x1.x,0.f)); a[5]=f2bf(fmaxf(x1.y,0.f));
        a[6]=f2bf(fmaxf(x1.z,0.f)); a[7]=f2bf(fmaxf(x1.w,0.f));

#pragma unroll
        for (int f = 0; f < 3; ++f) {
            bf16x8 b = *(const bf16x8*)(bp + (size_t)f * 16 * 128 + k0);
            acc[f] = __builtin_amdgcn_mfma_f32_16x16x32_bf16(a, b, acc[f], 0, 0, 0);
        }
    }

#pragma unroll
    for (int r = 0; r < 4; ++r) {
        const int row = row0 + l4 * 4 + r;
        if (row < M) {
#pragma unroll
            for (int f = 0; f < 3; ++f) {
                const int col = f * 16 + l15;
                if (col < 40)
                    Yb[(size_t)row * 40 + col] = (unsigned short)f2bf(acc[f][r]);
            }
        }
    }
}

// ---------------- segment2: out[r] = b2 + sum_j w_j * hw2b[col_j]  (bf16 gather, x4) ----------------
__global__ __launch_bounds__(256) void segment2_kernel(
    const int* __restrict__ rowptr, const int2* __restrict__ se,
    const unsigned* __restrict__ hw2b, const float* __restrict__ b2,
    float* __restrict__ out, int N)
{
    const int w    = threadIdx.x >> 6;
    const int lane = threadIdx.x & 63;      // lanes 0..19: feat pair (2*lane, 2*lane+1)
    const int r = blockIdx.x * 4 + w;
    if (r >= N || lane >= 20) return;
    float2 bb = *(const float2*)(b2 + 2 * lane);
    float acc0 = bb.x, acc1 = bb.y;
    int j = rowptr[r];
    const int end = rowptr[r + 1];
    for (; j + 3 < end; j += 4) {
        const int2 e0 = se[j], e1 = se[j + 1], e2 = se[j + 2], e3 = se[j + 3];
        const unsigned u0 = hw2b[(size_t)e0.x * 20 + lane];
        const unsigned u1 = hw2b[(size_t)e1.x * 20 + lane];
        const unsigned u2 = hw2b[(size_t)e2.x * 20 + lane];
        const unsigned u3 = hw2b[(size_t)e3.x * 20 + lane];
        const float w0 = __int_as_float(e0.y), w1 = __int_as_float(e1.y);
        const float w2 = __int_as_float(e2.y), w3 = __int_as_float(e3.y);
        acc0 = fmaf(w0, bflo(u0), acc0); acc1 = fmaf(w0, bfhi(u0), acc1);
        acc0 = fmaf(w1, bflo(u1), acc0); acc1 = fmaf(w1, bfhi(u1), acc1);
        acc0 = fmaf(w2, bflo(u2), acc0); acc1 = fmaf(w2, bfhi(u2), acc1);
        acc0 = fmaf(w3, bflo(u3), acc0); acc1 = fmaf(w3, bfhi(u3), acc1);
    }
    for (; j < end; ++j) {
        const int2 e = se[j];
        const unsigned u = hw2b[(size_t)e.x * 20 + lane];
        const float wt = __int_as_float(e.y);
        acc0 = fmaf(wt, bflo(u), acc0); acc1 = fmaf(wt, bfhi(u), acc1);
    }
    *(float2*)(out + (size_t)r * 40 + 2 * lane) = make_float2(acc0, acc1);
}

extern "C" void kernel_launch(void* const* d_in, const int* in_sizes, int n_in,
                              void* d_out, int out_size, void* d_ws, size_t ws_size,
                              hipStream_t stream)
{
    const float* x  = (const float*)d_in[0];
    const int* erow = (const int*)d_in[1];
    const int* ecol = (const int*)d_in[2];
    const float* ew = (const float*)d_in[3];
    const float* w1 = (const float*)d_in[4];
    const float* b1 = (const float*)d_in[5];
    const float* w2 = (const float*)d_in[6];
    const float* b2 = (const float*)d_in[7];
    float* out = (float*)d_out;

    const int N = in_sizes[0] / 512;   // 50000
    const int E = in_sizes[1];         // 800000
    const int NB = (N + 255) / 256;    // 196 (<=256 for scan2)

    // workspace layout (16B-aligned segments)
    short* w1t  = (short*)d_ws;                      // 128*512 bf16
    short* w2t  = w1t + 65536;                       // 48*128 bf16 (+pad)
    short* xw1b = w2t + 8192;                        // N*128 bf16
    float* h    = (float*)(xw1b + (size_t)N * 128);  // N*128 f32
    int* rowptr = (int*)(h + (size_t)N * 128);       // N+1
    int* cur    = rowptr + (N + 1);                  // N
    int* bsum   = cur + N;                           // 256 (+pad to 8B align)
    int2* se    = (int2*)(bsum + 256 + ((N + 1) & 1)); // E packed edges
    short* hw2b = xw1b;                              // N*40 bf16 (reuse)

    // CSR build
    zero_kernel<<<NB, 256, 0, stream>>>(cur, N);
    hist_kernel<<<(E + 255) / 256, 256, 0, stream>>>(erow, cur, E);
    scan1_kernel<<<NB, 256, 0, stream>>>(cur, rowptr, bsum, N);
    scan2_kernel<<<1, 256, 0, stream>>>(bsum, NB);
    scan3_kernel<<<NB, 256, 0, stream>>>(rowptr, bsum, cur, N, E);
    sortedges_kernel<<<(E + 255) / 256, 256, 0, stream>>>(erow, ecol, ew, cur, se, E);

    // weights
    w1t_kernel<<<256, 256, 0, stream>>>(w1, w1t);
    w2t_kernel<<<24, 256, 0, stream>>>(w2, w2t);

    // layer 1
    gemm1_mfma_kernel<<<(N + 63) / 64, 256, 0, stream>>>(x, w1t, xw1b, N);
    segment1_kernel<<<(N + 3) / 4, 256, 0, stream>>>(rowptr, se,
                                                     (const unsigned*)xw1b, b1, h, N);

    // layer 2
    gemm2_mfma_kernel<<<(N + 63) / 64, 256, 0, stream>>>(h, w2t,
                                                         (unsigned short*)hw2b, N);
    segment2_kernel<<<(N + 3) / 4, 256, 0, stream>>>(rowptr, se,
                                                     (const unsigned*)hw2b, b2, out, N);
}

// Round 7
// 223.793 us; speedup vs baseline: 2.7098x; 1.0440x over previous
//
#include <hip/hip_runtime.h>
#include <hip/hip_bf16.h>
#include <cstddef>

// GCN forward: out = A·(relu(A·(X·W1)+b1))·W2 + b2
// NFEAT=512, NHID=128, NCLS=40 hard-wired; N,E from in_sizes.
// CSR (counting sort) -> segment-sum SpMM.
// GEMMs: whole (pre-swizzled) weight in LDS once, barrier-free streaming K-loop,
// A global->reg (each X/H row read exactly once), bf16 MFMA 16x16x32.

typedef float f32x4 __attribute__((ext_vector_type(4)));
typedef short bf16x8 __attribute__((ext_vector_type(8)));

static __device__ __forceinline__ short f2bf(float f) {
    __hip_bfloat16 b = __float2bfloat16(f);
    return *reinterpret_cast<short*>(&b);
}
static __device__ __forceinline__ float bflo(unsigned u) {
    union { unsigned i; float f; } v; v.i = u << 16; return v.f;
}
static __device__ __forceinline__ float bfhi(unsigned u) {
    union { unsigned i; float f; } v; v.i = u & 0xFFFF0000u; return v.f;
}

typedef const __attribute__((address_space(1))) void* gas_ptr;
typedef __attribute__((address_space(3))) void* las_ptr;
static __device__ __forceinline__ void gload16(const void* g, void* l) {
    // async global->LDS, 16B per lane; LDS dest = wave-uniform base + lane*16
    __builtin_amdgcn_global_load_lds((gas_ptr)g, (las_ptr)l, 16, 0, 0);
}

// ---- W1 [512][128] f32 -> W1Ts: swizzled bf16 image of W1T[128][512] ----
// phys_short = (n*512 + k) ^ ((n&7)<<3)  (XOR within 128B groups, bank-spread)
__global__ __launch_bounds__(256) void w1t_kernel(const float* __restrict__ W1,
                                                  short* __restrict__ W1Ts)
{
    int idx = blockIdx.x * 256 + threadIdx.x;   // 65536 total
    int k = idx >> 7, n = idx & 127;
    int lin = n * 512 + k;
    W1Ts[lin ^ ((n & 7) << 3)] = f2bf(W1[idx]);
}

// ---- W2 [128][40] f32 -> W2Ts: swizzled bf16 image of W2T[48][128] (pad cols 40..47=0) ----
__global__ __launch_bounds__(256) void w2t_kernel(const float* __restrict__ W2,
                                                  short* __restrict__ W2Ts)
{
    int idx = blockIdx.x * 256 + threadIdx.x;   // 6144 total
    if (idx >= 48 * 128) return;
    int n = idx >> 7, k = idx & 127;
    W2Ts[idx ^ ((n & 7) << 3)] = (n < 40) ? f2bf(W2[k * 40 + n]) : (short)0;
}

// ---------------- GEMM1: XW1b[M,128](bf16) = X[M,512](f32) @ W1 ----------------
// Block 256thr/4 waves; wave = 16 rows x 128 cols (8 frags). Whole W1Ts in LDS (128KB).
// No barriers in K-loop -> compiler pipelines the A global-load stream freely.
__global__ __launch_bounds__(256, 1) void gemm1_mfma_kernel(
    const float* __restrict__ X, const short* __restrict__ W1Ts,
    short* __restrict__ XW1b, int M)
{
    __shared__ __align__(16) short Bs[128 * 512];   // 128 KB, pre-swizzled

    const int tid = threadIdx.x;
    const int w   = tid >> 6;
    const int l   = tid & 63;
    const int l15 = l & 15;
    const int l4  = l >> 4;
    const int row0 = blockIdx.x * 64 + w * 16;

    // linear 128KB copy global->LDS (layout already swizzled in global)
    {
        const char* src = (const char*)W1Ts;
        char* dst = (char*)Bs;
#pragma unroll
        for (int i = 0; i < 32; ++i)
            gload16(src + i * 4096 + tid * 16, dst + i * 4096 + tid * 16);
    }
    __syncthreads();

    f32x4 acc[8];
#pragma unroll
    for (int f = 0; f < 8; ++f) acc[f] = (f32x4)0.f;

    const int rr = row0 + l15;
    const int cr = rr < M ? rr : M - 1;      // clamp: loads unconditional
    const float* ap = X + (size_t)cr * 512 + l4 * 8;
    const int swz = (l15 & 7) << 3;

#pragma unroll
    for (int kt = 0; kt < 16; ++kt) {
        const float4 x0 = *(const float4*)(ap + kt * 32);
        const float4 x1 = *(const float4*)(ap + kt * 32 + 4);
        bf16x8 a;
        a[0]=f2bf(x0.x); a[1]=f2bf(x0.y); a[2]=f2bf(x0.z); a[3]=f2bf(x0.w);
        a[4]=f2bf(x1.x); a[5]=f2bf(x1.y); a[6]=f2bf(x1.z); a[7]=f2bf(x1.w);

#pragma unroll
        for (int f = 0; f < 8; ++f) {
            const int si = ((f * 16 + l15) * 512 + kt * 32 + l4 * 8) ^ swz;
            const bf16x8 b = *(const bf16x8*)&Bs[si];
            acc[f] = __builtin_amdgcn_mfma_f32_16x16x32_bf16(a, b, acc[f], 0, 0, 0);
        }
    }

    // D layout: col = lane&15, row = (lane>>4)*4 + reg
#pragma unroll
    for (int r = 0; r < 4; ++r) {
        const int row = row0 + l4 * 4 + r;
        if (row < M) {
#pragma unroll
            for (int f = 0; f < 8; ++f)
                XW1b[(size_t)row * 128 + f * 16 + l15] = f2bf(acc[f][r]);
        }
    }
}

// ---------------- CSR build ----------------
__global__ __launch_bounds__(256) void zero_kernel(int* __restrict__ p, int n)
{
    int i = blockIdx.x * 256 + threadIdx.x;
    if (i < n) p[i] = 0;
}

__global__ __launch_bounds__(256) void hist_kernel(const int* __restrict__ row,
                                                   int* __restrict__ counts, int E)
{
    int e = blockIdx.x * 256 + threadIdx.x;
    if (e < E) atomicAdd(&counts[row[e]], 1);
}

__global__ __launch_bounds__(256) void scan1_kernel(const int* __restrict__ counts,
                                                    int* __restrict__ excl,
                                                    int* __restrict__ bsum, int N)
{
    __shared__ int s[256];
    const int t = threadIdx.x;
    const int i = blockIdx.x * 256 + t;
    int v = (i < N) ? counts[i] : 0;
    s[t] = v; __syncthreads();
#pragma unroll
    for (int off = 1; off < 256; off <<= 1) {
        int tmp = (t >= off) ? s[t - off] : 0;
        __syncthreads();
        s[t] += tmp;
        __syncthreads();
    }
    if (i < N) excl[i] = s[t] - v;
    if (t == 255) bsum[blockIdx.x] = s[255];
}

__global__ __launch_bounds__(256) void scan2_kernel(int* __restrict__ bsum, int NB)
{
    __shared__ int s[256];
    const int t = threadIdx.x;
    int v = (t < NB) ? bsum[t] : 0;
    s[t] = v; __syncthreads();
#pragma unroll
    for (int off = 1; off < 256; off <<= 1) {
        int tmp = (t >= off) ? s[t - off] : 0;
        __syncthreads();
        s[t] += tmp;
        __syncthreads();
    }
    if (t < NB) bsum[t] = s[t] - v;
}

__global__ __launch_bounds__(256) void scan3_kernel(int* __restrict__ rowptr,
                                                    const int* __restrict__ bsum,
                                                    int* __restrict__ cur, int N, int E)
{
    int i = blockIdx.x * 256 + threadIdx.x;
    if (i < N) {
        int v = rowptr[i] + bsum[blockIdx.x];
        rowptr[i] = v;
        cur[i] = v;
    }
    if (i == 0) rowptr[N] = E;
}

__global__ __launch_bounds__(256) void sortedges_kernel(
    const int* __restrict__ row, const int* __restrict__ col,
    const float* __restrict__ w, int* __restrict__ cur,
    int2* __restrict__ se, int E)
{
    int e = blockIdx.x * 256 + threadIdx.x;
    if (e < E) {
        int r = row[e];
        int pos = atomicAdd(&cur[r], 1);
        se[pos] = make_int2(col[e], __float_as_int(w[e]));
    }
}

// ---------------- segment1: h[r] = b1 + sum_j w_j * xw1b[col_j]  (bf16 gather, x4) ----------------
__global__ __launch_bounds__(256) void segment1_kernel(
    const int* __restrict__ rowptr, const int2* __restrict__ se,
    const unsigned* __restrict__ xw1b, const float* __restrict__ b1,
    float* __restrict__ h, int N)
{
    const int w    = threadIdx.x >> 6;
    const int lane = threadIdx.x & 63;      // feat pair (2*lane, 2*lane+1)
    const int r = blockIdx.x * 4 + w;
    if (r >= N) return;
    float2 bb = *(const float2*)(b1 + 2 * lane);
    float acc0 = bb.x, acc1 = bb.y;
    int j = rowptr[r];
    const int end = rowptr[r + 1];
    for (; j + 3 < end; j += 4) {
        const int2 e0 = se[j], e1 = se[j + 1], e2 = se[j + 2], e3 = se[j + 3];
        const unsigned u0 = xw1b[(size_t)e0.x * 64 + lane];
        const unsigned u1 = xw1b[(size_t)e1.x * 64 + lane];
        const unsigned u2 = xw1b[(size_t)e2.x * 64 + lane];
        const unsigned u3 = xw1b[(size_t)e3.x * 64 + lane];
        const float w0 = __int_as_float(e0.y), w1 = __int_as_float(e1.y);
        const float w2 = __int_as_float(e2.y), w3 = __int_as_float(e3.y);
        acc0 = fmaf(w0, bflo(u0), acc0); acc1 = fmaf(w0, bfhi(u0), acc1);
        acc0 = fmaf(w1, bflo(u1), acc0); acc1 = fmaf(w1, bfhi(u1), acc1);
        acc0 = fmaf(w2, bflo(u2), acc0); acc1 = fmaf(w2, bfhi(u2), acc1);
        acc0 = fmaf(w3, bflo(u3), acc0); acc1 = fmaf(w3, bfhi(u3), acc1);
    }
    for (; j < end; ++j) {
        const int2 e = se[j];
        const unsigned u = xw1b[(size_t)e.x * 64 + lane];
        const float wt = __int_as_float(e.y);
        acc0 = fmaf(wt, bflo(u), acc0); acc1 = fmaf(wt, bfhi(u), acc1);
    }
    *(float2*)(h + (size_t)r * 128 + 2 * lane) = make_float2(acc0, acc1);
}

// ---------------- GEMM2: Yb[M,40](bf16) = relu(H[M,128]) @ W2 ----------------
// Same template: whole W2Ts (12KB) in LDS, barrier-free unrolled K-loop.
__global__ __launch_bounds__(256) void gemm2_mfma_kernel(
    const float* __restrict__ H, const short* __restrict__ W2Ts,
    unsigned short* __restrict__ Yb, int M)
{
    __shared__ __align__(16) short Ws[48 * 128];   // 12 KB, pre-swizzled

    const int tid = threadIdx.x;
    const int w   = tid >> 6;
    const int l   = tid & 63;
    const int l15 = l & 15;
    const int l4  = l >> 4;
    const int row0 = blockIdx.x * 64 + w * 16;

    {
        const char* src = (const char*)W2Ts;
        char* dst = (char*)Ws;
#pragma unroll
        for (int i = 0; i < 3; ++i)
            gload16(src + i * 4096 + tid * 16, dst + i * 4096 + tid * 16);
    }
    __syncthreads();

    f32x4 acc[3];
#pragma unroll
    for (int f = 0; f < 3; ++f) acc[f] = (f32x4)0.f;

    const int rr = row0 + l15;
    const int cr = rr < M ? rr : M - 1;
    const float* hp = H + (size_t)cr * 128 + l4 * 8;
    const int swz = (l15 & 7) << 3;

#pragma unroll
    for (int kt = 0; kt < 4; ++kt) {
        const float4 x0 = *(const float4*)(hp + kt * 32);
        const float4 x1 = *(const float4*)(hp + kt * 32 + 4);
        bf16x8 a;
        a[0]=f2bf(fmaxf(x0.x,0.f)); a[1]=f2bf(fmaxf(x0.y,0.f));
        a[2]=f2bf(fmaxf(x0.z,0.f)); a[3]=f2bf(fmaxf(x0.w,0.f));
        a[4]=f2bf(fmaxf(x1.x,0.f)); a[5]=f2bf(fmaxf(x1.y,0.f));
        a[6]=f2bf(fmaxf(x1.z,0.f)); a[7]=f2bf(fmaxf(x1.w,0.f));

#pragma unroll
        for (int f = 0; f < 3; ++f) {
            const int si = ((f * 16 + l15) * 128 + kt * 32 + l4 * 8) ^ swz;
            const bf16x8 b = *(const bf16x8*)&Ws[si];
            acc[f] = __builtin_amdgcn_mfma_f32_16x16x32_bf16(a, b, acc[f], 0, 0, 0);
        }
    }

#pragma unroll
    for (int r = 0; r < 4; ++r) {
        const int row = row0 + l4 * 4 + r;
        if (row < M) {
#pragma unroll
            for (int f = 0; f < 3; ++f) {
                const int col = f * 16 + l15;
                if (col < 40)
                    Yb[(size_t)row * 40 + col] = (unsigned short)f2bf(acc[f][r]);
            }
        }
    }
}

// ---------------- segment2: out[r] = b2 + sum_j w_j * hw2b[col_j]  (bf16 gather, x4) ----------------
__global__ __launch_bounds__(256) void segment2_kernel(
    const int* __restrict__ rowptr, const int2* __restrict__ se,
    const unsigned* __restrict__ hw2b, const float* __restrict__ b2,
    float* __restrict__ out, int N)
{
    const int w    = threadIdx.x >> 6;
    const int lane = threadIdx.x & 63;      // lanes 0..19: feat pair (2*lane, 2*lane+1)
    const int r = blockIdx.x * 4 + w;
    if (r >= N || lane >= 20) return;
    float2 bb = *(const float2*)(b2 + 2 * lane);
    float acc0 = bb.x, acc1 = bb.y;
    int j = rowptr[r];
    const int end = rowptr[r + 1];
    for (; j + 3 < end; j += 4) {
        const int2 e0 = se[j], e1 = se[j + 1], e2 = se[j + 2], e3 = se[j + 3];
        const unsigned u0 = hw2b[(size_t)e0.x * 20 + lane];
        const unsigned u1 = hw2b[(size_t)e1.x * 20 + lane];
        const unsigned u2 = hw2b[(size_t)e2.x * 20 + lane];
        const unsigned u3 = hw2b[(size_t)e3.x * 20 + lane];
        const float w0 = __int_as_float(e0.y), w1 = __int_as_float(e1.y);
        const float w2 = __int_as_float(e2.y), w3 = __int_as_float(e3.y);
        acc0 = fmaf(w0, bflo(u0), acc0); acc1 = fmaf(w0, bfhi(u0), acc1);
        acc0 = fmaf(w1, bflo(u1), acc0); acc1 = fmaf(w1, bfhi(u1), acc1);
        acc0 = fmaf(w2, bflo(u2), acc0); acc1 = fmaf(w2, bfhi(u2), acc1);
        acc0 = fmaf(w3, bflo(u3), acc0); acc1 = fmaf(w3, bfhi(u3), acc1);
    }
    for (; j < end; ++j) {
        const int2 e = se[j];
        const unsigned u = hw2b[(size_t)e.x * 20 + lane];
        const float wt = __int_as_float(e.y);
        acc0 = fmaf(wt, bflo(u), acc0); acc1 = fmaf(wt, bfhi(u), acc1);
    }
    *(float2*)(out + (size_t)r * 40 + 2 * lane) = make_float2(acc0, acc1);
}

extern "C" void kernel_launch(void* const* d_in, const int* in_sizes, int n_in,
                              void* d_out, int out_size, void* d_ws, size_t ws_size,
                              hipStream_t stream)
{
    const float* x  = (const float*)d_in[0];
    const int* erow = (const int*)d_in[1];
    const int* ecol = (const int*)d_in[2];
    const float* ew = (const float*)d_in[3];
    const float* w1 = (const float*)d_in[4];
    const float* b1 = (const float*)d_in[5];
    const float* w2 = (const float*)d_in[6];
    const float* b2 = (const float*)d_in[7];
    float* out = (float*)d_out;

    const int N = in_sizes[0] / 512;   // 50000
    const int E = in_sizes[1];         // 800000
    const int NB = (N + 255) / 256;    // 196 (<=256 for scan2)

    // workspace layout (16B-aligned segments)
    short* w1ts = (short*)d_ws;                      // 128*512 bf16 (swizzled)
    short* w2ts = w1ts + 65536;                      // 48*128 bf16 (swizzled, +pad)
    short* xw1b = w2ts + 8192;                       // N*128 bf16
    float* h    = (float*)(xw1b + (size_t)N * 128);  // N*128 f32
    int* rowptr = (int*)(h + (size_t)N * 128);       // N+1
    int* cur    = rowptr + (N + 1);                  // N
    int* bsum   = cur + N;                           // 256 (+pad to 8B align)
    int2* se    = (int2*)(bsum + 256 + ((N + 1) & 1)); // E packed edges
    short* hw2b = xw1b;                              // N*40 bf16 (reuse)

    // CSR build
    zero_kernel<<<NB, 256, 0, stream>>>(cur, N);
    hist_kernel<<<(E + 255) / 256, 256, 0, stream>>>(erow, cur, E);
    scan1_kernel<<<NB, 256, 0, stream>>>(cur, rowptr, bsum, N);
    scan2_kernel<<<1, 256, 0, stream>>>(bsum, NB);
    scan3_kernel<<<NB, 256, 0, stream>>>(rowptr, bsum, cur, N, E);
    sortedges_kernel<<<(E + 255) / 256, 256, 0, stream>>>(erow, ecol, ew, cur, se, E);

    // weights (pre-transposed + bank-swizzled bf16 images)
    w1t_kernel<<<256, 256, 0, stream>>>(w1, w1ts);
    w2t_kernel<<<24, 256, 0, stream>>>(w2, w2ts);

    // layer 1
    gemm1_mfma_kernel<<<(N + 63) / 64, 256, 0, stream>>>(x, w1ts, xw1b, N);
    segment1_kernel<<<(N + 3) / 4, 256, 0, stream>>>(rowptr, se,
                                                     (const unsigned*)xw1b, b1, h, N);

    // layer 2
    gemm2_mfma_kernel<<<(N + 63) / 64, 256, 0, stream>>>(h, w2ts,
                                                         (unsigned short*)hw2b, N);
    segment2_kernel<<<(N + 3) / 4, 256, 0, stream>>>(rowptr, se,
                                                     (const unsigned*)hw2b, b2, out, N);
}

// Round 8
// 217.927 us; speedup vs baseline: 2.7827x; 1.0269x over previous
//
#include <hip/hip_runtime.h>
#include <hip/hip_bf16.h>
#include <cstddef>

// GCN forward: out = A·(relu(A·(X·W1)+b1))·W2 + b2
// NFEAT=512, NHID=128, NCLS=40 hard-wired; N,E from in_sizes.
// CSR (counting sort) -> segment-sum SpMM.
// gemm1: whole pre-swizzled W1T in LDS (128KB), 1024-thr block (16 waves/CU),
// barrier-free streaming K-loop, A global->reg, bf16 MFMA 16x16x32.

typedef float f32x4 __attribute__((ext_vector_type(4)));
typedef short bf16x8 __attribute__((ext_vector_type(8)));

static __device__ __forceinline__ short f2bf(float f) {
    __hip_bfloat16 b = __float2bfloat16(f);
    return *reinterpret_cast<short*>(&b);
}
static __device__ __forceinline__ float bflo(unsigned u) {
    union { unsigned i; float f; } v; v.i = u << 16; return v.f;
}
static __device__ __forceinline__ float bfhi(unsigned u) {
    union { unsigned i; float f; } v; v.i = u & 0xFFFF0000u; return v.f;
}

typedef const __attribute__((address_space(1))) void* gas_ptr;
typedef __attribute__((address_space(3))) void* las_ptr;
static __device__ __forceinline__ void gload16(const void* g, void* l) {
    __builtin_amdgcn_global_load_lds((gas_ptr)g, (las_ptr)l, 16, 0, 0);
}

// ---- W1 [512][128] f32 -> W1Ts: swizzled bf16 image of W1T[128][512] ----
// phys_short = (n*512 + k) ^ ((n&7)<<3)
__global__ __launch_bounds__(256) void w1t_kernel(const float* __restrict__ W1,
                                                  short* __restrict__ W1Ts)
{
    int idx = blockIdx.x * 256 + threadIdx.x;   // 65536 total
    int k = idx >> 7, n = idx & 127;
    int lin = n * 512 + k;
    W1Ts[lin ^ ((n & 7) << 3)] = f2bf(W1[idx]);
}

// ---- W2 [128][40] f32 -> W2Ts: swizzled bf16 image of W2T[48][128] ----
__global__ __launch_bounds__(256) void w2t_kernel(const float* __restrict__ W2,
                                                  short* __restrict__ W2Ts)
{
    int idx = blockIdx.x * 256 + threadIdx.x;   // 6144 total
    if (idx >= 48 * 128) return;
    int n = idx >> 7, k = idx & 127;
    W2Ts[idx ^ ((n & 7) << 3)] = (n < 40) ? f2bf(W2[k * 40 + n]) : (short)0;
}

// ---------------- GEMM1: XW1b[M,128](bf16) = X[M,512](f32) @ W1 ----------------
// 1024 threads = 16 waves (8 row-groups x 2 col-halves); wave = 16r x 64c (4 frags).
// Whole W1Ts in LDS; no barriers in K-loop.
__global__ __launch_bounds__(1024, 4) void gemm1_mfma_kernel(
    const float* __restrict__ X, const short* __restrict__ W1Ts,
    short* __restrict__ XW1b, int M)
{
    __shared__ __align__(16) short Bs[128 * 512];   // 128 KB, pre-swizzled

    const int tid = threadIdx.x;
    const int w   = tid >> 6;          // 0..15
    const int l   = tid & 63;
    const int l15 = l & 15;
    const int l4  = l >> 4;
    const int row0 = blockIdx.x * 128 + (w >> 1) * 16;
    const int col0 = (w & 1) * 64;

    // linear 128KB copy global->LDS (layout already swizzled in global)
    {
        const char* src = (const char*)W1Ts;
        char* dst = (char*)Bs;
#pragma unroll
        for (int i = 0; i < 8; ++i)
            gload16(src + i * 16384 + tid * 16, dst + i * 16384 + tid * 16);
    }
    __syncthreads();

    f32x4 acc[4];
#pragma unroll
    for (int f = 0; f < 4; ++f) acc[f] = (f32x4)0.f;

    const int rr = row0 + l15;
    const int cr = rr < M ? rr : M - 1;      // clamp: loads unconditional
    const float* ap = X + (size_t)cr * 512 + l4 * 8;
    const int swz = (l15 & 7) << 3;

#pragma unroll
    for (int kt = 0; kt < 16; ++kt) {
        const float4 x0 = *(const float4*)(ap + kt * 32);
        const float4 x1 = *(const float4*)(ap + kt * 32 + 4);
        bf16x8 a;
        a[0]=f2bf(x0.x); a[1]=f2bf(x0.y); a[2]=f2bf(x0.z); a[3]=f2bf(x0.w);
        a[4]=f2bf(x1.x); a[5]=f2bf(x1.y); a[6]=f2bf(x1.z); a[7]=f2bf(x1.w);

#pragma unroll
        for (int f = 0; f < 4; ++f) {
            const int si = ((col0 + f * 16 + l15) * 512 + kt * 32 + l4 * 8) ^ swz;
            const bf16x8 b = *(const bf16x8*)&Bs[si];
            acc[f] = __builtin_amdgcn_mfma_f32_16x16x32_bf16(a, b, acc[f], 0, 0, 0);
        }
    }

    // D layout: col = lane&15, row = (lane>>4)*4 + reg
#pragma unroll
    for (int r = 0; r < 4; ++r) {
        const int row = row0 + l4 * 4 + r;
        if (row < M) {
#pragma unroll
            for (int f = 0; f < 4; ++f)
                XW1b[(size_t)row * 128 + col0 + f * 16 + l15] = f2bf(acc[f][r]);
        }
    }
}

// ---------------- CSR build ----------------
__global__ __launch_bounds__(256) void zero_kernel(int* __restrict__ p, int n)
{
    int i = blockIdx.x * 256 + threadIdx.x;
    if (i < n) p[i] = 0;
}

__global__ __launch_bounds__(256) void hist_kernel(const int* __restrict__ row,
                                                   int* __restrict__ counts, int E)
{
    int e = blockIdx.x * 256 + threadIdx.x;
    if (e < E) atomicAdd(&counts[row[e]], 1);
}

__global__ __launch_bounds__(256) void scan1_kernel(const int* __restrict__ counts,
                                                    int* __restrict__ excl,
                                                    int* __restrict__ bsum, int N)
{
    __shared__ int s[256];
    const int t = threadIdx.x;
    const int i = blockIdx.x * 256 + t;
    int v = (i < N) ? counts[i] : 0;
    s[t] = v; __syncthreads();
#pragma unroll
    for (int off = 1; off < 256; off <<= 1) {
        int tmp = (t >= off) ? s[t - off] : 0;
        __syncthreads();
        s[t] += tmp;
        __syncthreads();
    }
    if (i < N) excl[i] = s[t] - v;
    if (t == 255) bsum[blockIdx.x] = s[255];
}

__global__ __launch_bounds__(256) void scan2_kernel(int* __restrict__ bsum, int NB)
{
    __shared__ int s[256];
    const int t = threadIdx.x;
    int v = (t < NB) ? bsum[t] : 0;
    s[t] = v; __syncthreads();
#pragma unroll
    for (int off = 1; off < 256; off <<= 1) {
        int tmp = (t >= off) ? s[t - off] : 0;
        __syncthreads();
        s[t] += tmp;
        __syncthreads();
    }
    if (t < NB) bsum[t] = s[t] - v;
}

__global__ __launch_bounds__(256) void scan3_kernel(int* __restrict__ rowptr,
                                                    const int* __restrict__ bsum,
                                                    int* __restrict__ cur, int N, int E)
{
    int i = blockIdx.x * 256 + threadIdx.x;
    if (i < N) {
        int v = rowptr[i] + bsum[blockIdx.x];
        rowptr[i] = v;
        cur[i] = v;
    }
    if (i == 0) rowptr[N] = E;
}

__global__ __launch_bounds__(256) void sortedges_kernel(
    const int* __restrict__ row, const int* __restrict__ col,
    const float* __restrict__ w, int* __restrict__ cur,
    int2* __restrict__ se, int E)
{
    int e = blockIdx.x * 256 + threadIdx.x;
    if (e < E) {
        int r = row[e];
        int pos = atomicAdd(&cur[r], 1);
        se[pos] = make_int2(col[e], __float_as_int(w[e]));
    }
}

// ---------------- segment1: h[r] = b1 + sum_j w_j * xw1b[col_j]  (bf16 gather, x4) ----------------
__global__ __launch_bounds__(256) void segment1_kernel(
    const int* __restrict__ rowptr, const int2* __restrict__ se,
    const unsigned* __restrict__ xw1b, const float* __restrict__ b1,
    float* __restrict__ h, int N)
{
    const int w    = threadIdx.x >> 6;
    const int lane = threadIdx.x & 63;      // feat pair (2*lane, 2*lane+1)
    const int r = blockIdx.x * 4 + w;
    if (r >= N) return;
    float2 bb = *(const float2*)(b1 + 2 * lane);
    float acc0 = bb.x, acc1 = bb.y;
    int j = rowptr[r];
    const int end = rowptr[r + 1];
    for (; j + 3 < end; j += 4) {
        const int2 e0 = se[j], e1 = se[j + 1], e2 = se[j + 2], e3 = se[j + 3];
        const unsigned u0 = xw1b[(size_t)e0.x * 64 + lane];
        const unsigned u1 = xw1b[(size_t)e1.x * 64 + lane];
        const unsigned u2 = xw1b[(size_t)e2.x * 64 + lane];
        const unsigned u3 = xw1b[(size_t)e3.x * 64 + lane];
        const float w0 = __int_as_float(e0.y), w1 = __int_as_float(e1.y);
        const float w2 = __int_as_float(e2.y), w3 = __int_as_float(e3.y);
        acc0 = fmaf(w0, bflo(u0), acc0); acc1 = fmaf(w0, bfhi(u0), acc1);
        acc0 = fmaf(w1, bflo(u1), acc0); acc1 = fmaf(w1, bfhi(u1), acc1);
        acc0 = fmaf(w2, bflo(u2), acc0); acc1 = fmaf(w2, bfhi(u2), acc1);
        acc0 = fmaf(w3, bflo(u3), acc0); acc1 = fmaf(w3, bfhi(u3), acc1);
    }
    for (; j < end; ++j) {
        const int2 e = se[j];
        const unsigned u = xw1b[(size_t)e.x * 64 + lane];
        const float wt = __int_as_float(e.y);
        acc0 = fmaf(wt, bflo(u), acc0); acc1 = fmaf(wt, bfhi(u), acc1);
    }
    *(float2*)(h + (size_t)r * 128 + 2 * lane) = make_float2(acc0, acc1);
}

// ---------------- GEMM2: Yb[M,40](bf16) = relu(H[M,128]) @ W2 ----------------
__global__ __launch_bounds__(256) void gemm2_mfma_kernel(
    const float* __restrict__ H, const short* __restrict__ W2Ts,
    unsigned short* __restrict__ Yb, int M)
{
    __shared__ __align__(16) short Ws[48 * 128];   // 12 KB, pre-swizzled

    const int tid = threadIdx.x;
    const int w   = tid >> 6;
    const int l   = tid & 63;
    const int l15 = l & 15;
    const int l4  = l >> 4;
    const int row0 = blockIdx.x * 64 + w * 16;

    {
        const char* src = (const char*)W2Ts;
        char* dst = (char*)Ws;
#pragma unroll
        for (int i = 0; i < 3; ++i)
            gload16(src + i * 4096 + tid * 16, dst + i * 4096 + tid * 16);
    }
    __syncthreads();

    f32x4 acc[3];
#pragma unroll
    for (int f = 0; f < 3; ++f) acc[f] = (f32x4)0.f;

    const int rr = row0 + l15;
    const int cr = rr < M ? rr : M - 1;
    const float* hp = H + (size_t)cr * 128 + l4 * 8;
    const int swz = (l15 & 7) << 3;

#pragma unroll
    for (int kt = 0; kt < 4; ++kt) {
        const float4 x0 = *(const float4*)(hp + kt * 32);
        const float4 x1 = *(const float4*)(hp + kt * 32 + 4);
        bf16x8 a;
        a[0]=f2bf(fmaxf(x0.x,0.f)); a[1]=f2bf(fmaxf(x0.y,0.f));
        a[2]=f2bf(fmaxf(x0.z,0.f)); a[3]=f2bf(fmaxf(x0.w,0.f));
        a[4]=f2bf(fmaxf(x1.x,0.f)); a[5]=f2bf(fmaxf(x1.y,0.f));
        a[6]=f2bf(fmaxf(x1.z,0.f)); a[7]=f2bf(fmaxf(x1.w,0.f));

#pragma unroll
        for (int f = 0; f < 3; ++f) {
            const int si = ((f * 16 + l15) * 128 + kt * 32 + l4 * 8) ^ swz;
            const bf16x8 b = *(const bf16x8*)&Ws[si];
            acc[f] = __builtin_amdgcn_mfma_f32_16x16x32_bf16(a, b, acc[f], 0, 0, 0);
        }
    }

#pragma unroll
    for (int r = 0; r < 4; ++r) {
        const int row = row0 + l4 * 4 + r;
        if (row < M) {
#pragma unroll
            for (int f = 0; f < 3; ++f) {
                const int col = f * 16 + l15;
                if (col < 40)
                    Yb[(size_t)row * 40 + col] = (unsigned short)f2bf(acc[f][r]);
            }
        }
    }
}

// ---------------- segment2: out[r] = b2 + sum_j w_j * hw2b[col_j]  (bf16 gather, x4) ----------------
__global__ __launch_bounds__(256) void segment2_kernel(
    const int* __restrict__ rowptr, const int2* __restrict__ se,
    const unsigned* __restrict__ hw2b, const float* __restrict__ b2,
    float* __restrict__ out, int N)
{
    const int w    = threadIdx.x >> 6;
    const int lane = threadIdx.x & 63;      // lanes 0..19: feat pair (2*lane, 2*lane+1)
    const int r = blockIdx.x * 4 + w;
    if (r >= N || lane >= 20) return;
    float2 bb = *(const float2*)(b2 + 2 * lane);
    float acc0 = bb.x, acc1 = bb.y;
    int j = rowptr[r];
    const int end = rowptr[r + 1];
    for (; j + 3 < end; j += 4) {
        const int2 e0 = se[j], e1 = se[j + 1], e2 = se[j + 2], e3 = se[j + 3];
        const unsigned u0 = hw2b[(size_t)e0.x * 20 + lane];
        const unsigned u1 = hw2b[(size_t)e1.x * 20 + lane];
        const unsigned u2 = hw2b[(size_t)e2.x * 20 + lane];
        const unsigned u3 = hw2b[(size_t)e3.x * 20 + lane];
        const float w0 = __int_as_float(e0.y), w1 = __int_as_float(e1.y);
        const float w2 = __int_as_float(e2.y), w3 = __int_as_float(e3.y);
        acc0 = fmaf(w0, bflo(u0), acc0); acc1 = fmaf(w0, bfhi(u0), acc1);
        acc0 = fmaf(w1, bflo(u1), acc0); acc1 = fmaf(w1, bfhi(u1), acc1);
        acc0 = fmaf(w2, bflo(u2), acc0); acc1 = fmaf(w2, bfhi(u2), acc1);
        acc0 = fmaf(w3, bflo(u3), acc0); acc1 = fmaf(w3, bfhi(u3), acc1);
    }
    for (; j < end; ++j) {
        const int2 e = se[j];
        const unsigned u = hw2b[(size_t)e.x * 20 + lane];
        const float wt = __int_as_float(e.y);
        acc0 = fmaf(wt, bflo(u), acc0); acc1 = fmaf(wt, bfhi(u), acc1);
    }
    *(float2*)(out + (size_t)r * 40 + 2 * lane) = make_float2(acc0, acc1);
}

extern "C" void kernel_launch(void* const* d_in, const int* in_sizes, int n_in,
                              void* d_out, int out_size, void* d_ws, size_t ws_size,
                              hipStream_t stream)
{
    const float* x  = (const float*)d_in[0];
    const int* erow = (const int*)d_in[1];
    const int* ecol = (const int*)d_in[2];
    const float* ew = (const float*)d_in[3];
    const float* w1 = (const float*)d_in[4];
    const float* b1 = (const float*)d_in[5];
    const float* w2 = (const float*)d_in[6];
    const float* b2 = (const float*)d_in[7];
    float* out = (float*)d_out;

    const int N = in_sizes[0] / 512;   // 50000
    const int E = in_sizes[1];         // 800000
    const int NB = (N + 255) / 256;    // 196 (<=256 for scan2)

    // workspace layout (16B-aligned segments)
    short* w1ts = (short*)d_ws;                      // 128*512 bf16 (swizzled)
    short* w2ts = w1ts + 65536;                      // 48*128 bf16 (swizzled, +pad)
    short* xw1b = w2ts + 8192;                       // N*128 bf16
    float* h    = (float*)(xw1b + (size_t)N * 128);  // N*128 f32
    int* rowptr = (int*)(h + (size_t)N * 128);       // N+1
    int* cur    = rowptr + (N + 1);                  // N
    int* bsum   = cur + N;                           // 256 (+pad to 8B align)
    int2* se    = (int2*)(bsum + 256 + ((N + 1) & 1)); // E packed edges
    short* hw2b = xw1b;                              // N*40 bf16 (reuse)

    // CSR build
    zero_kernel<<<NB, 256, 0, stream>>>(cur, N);
    hist_kernel<<<(E + 255) / 256, 256, 0, stream>>>(erow, cur, E);
    scan1_kernel<<<NB, 256, 0, stream>>>(cur, rowptr, bsum, N);
    scan2_kernel<<<1, 256, 0, stream>>>(bsum, NB);
    scan3_kernel<<<NB, 256, 0, stream>>>(rowptr, bsum, cur, N, E);
    sortedges_kernel<<<(E + 255) / 256, 256, 0, stream>>>(erow, ecol, ew, cur, se, E);

    // weights (pre-transposed + bank-swizzled bf16 images)
    w1t_kernel<<<256, 256, 0, stream>>>(w1, w1ts);
    w2t_kernel<<<24, 256, 0, stream>>>(w2, w2ts);

    // layer 1
    gemm1_mfma_kernel<<<(N + 127) / 128, 1024, 0, stream>>>(x, w1ts, xw1b, N);
    segment1_kernel<<<(N + 3) / 4, 256, 0, stream>>>(rowptr, se,
                                                     (const unsigned*)xw1b, b1, h, N);

    // layer 2
    gemm2_mfma_kernel<<<(N + 63) / 64, 256, 0, stream>>>(h, w2ts,
                                                         (unsigned short*)hw2b, N);
    segment2_kernel<<<(N + 3) / 4, 256, 0, stream>>>(rowptr, se,
                                                     (const unsigned*)hw2b, b2, out, N);
}

// Round 9
// 206.426 us; speedup vs baseline: 2.9378x; 1.0557x over previous
//
#include <hip/hip_runtime.h>
#include <hip/hip_bf16.h>
#include <cstddef>

// GCN forward: out = A·(relu(A·(X·W1)+b1))·W2 + b2
// NFEAT=512, NHID=128, NCLS=40 hard-wired; N,E from in_sizes.
// CSR (counting sort) -> segment-sum SpMM (multi-edge-per-wave gathers).
// gemm1: whole pre-swizzled W1T in LDS, 1024-thr block, barrier-free K-loop.
// h stored as relu'd bf16 (exact vs reference: gemm2 casts to bf16 anyway).

typedef float f32x4 __attribute__((ext_vector_type(4)));
typedef short bf16x8 __attribute__((ext_vector_type(8)));

static __device__ __forceinline__ short f2bf(float f) {
    __hip_bfloat16 b = __float2bfloat16(f);
    return *reinterpret_cast<short*>(&b);
}
static __device__ __forceinline__ float bflo(unsigned u) {
    union { unsigned i; float f; } v; v.i = u << 16; return v.f;
}
static __device__ __forceinline__ float bfhi(unsigned u) {
    union { unsigned i; float f; } v; v.i = u & 0xFFFF0000u; return v.f;
}
static __device__ __forceinline__ unsigned pack2bf(float lo, float hi) {
    unsigned a = (unsigned short)f2bf(lo);
    unsigned b = (unsigned short)f2bf(hi);
    return a | (b << 16);
}

typedef const __attribute__((address_space(1))) void* gas_ptr;
typedef __attribute__((address_space(3))) void* las_ptr;
static __device__ __forceinline__ void gload16(const void* g, void* l) {
    __builtin_amdgcn_global_load_lds((gas_ptr)g, (las_ptr)l, 16, 0, 0);
}

// ---- prep: W1->W1Ts (swizzled bf16 W1T), W2->W2Ts, zero cur[] ----
__global__ __launch_bounds__(256) void prep_kernel(
    const float* __restrict__ W1, short* __restrict__ W1Ts,
    const float* __restrict__ W2, short* __restrict__ W2Ts,
    int* __restrict__ cur, int N)
{
    int idx = blockIdx.x * 256 + threadIdx.x;
    if (idx < 65536) {
        int k = idx >> 7, n = idx & 127;
        int lin = n * 512 + k;
        W1Ts[lin ^ ((n & 7) << 3)] = f2bf(W1[idx]);
    } else if (idx < 65536 + 6144) {
        int i2 = idx - 65536;
        int n = i2 >> 7, k = i2 & 127;
        W2Ts[i2 ^ ((n & 7) << 3)] = (n < 40) ? f2bf(W2[k * 40 + n]) : (short)0;
    } else if (idx < 65536 + 6144 + N) {
        cur[idx - 65536 - 6144] = 0;
    }
}

// ---------------- GEMM1: XW1b[M,128](bf16) = X[M,512](f32) @ W1 ----------------
__global__ __launch_bounds__(1024, 4) void gemm1_mfma_kernel(
    const float* __restrict__ X, const short* __restrict__ W1Ts,
    short* __restrict__ XW1b, int M)
{
    __shared__ __align__(16) short Bs[128 * 512];   // 128 KB, pre-swizzled

    const int tid = threadIdx.x;
    const int w   = tid >> 6;          // 0..15
    const int l   = tid & 63;
    const int l15 = l & 15;
    const int l4  = l >> 4;
    const int row0 = blockIdx.x * 128 + (w >> 1) * 16;
    const int col0 = (w & 1) * 64;

    {
        const char* src = (const char*)W1Ts;
        char* dst = (char*)Bs;
#pragma unroll
        for (int i = 0; i < 8; ++i)
            gload16(src + i * 16384 + tid * 16, dst + i * 16384 + tid * 16);
    }
    __syncthreads();

    f32x4 acc[4];
#pragma unroll
    for (int f = 0; f < 4; ++f) acc[f] = (f32x4)0.f;

    const int rr = row0 + l15;
    const int cr = rr < M ? rr : M - 1;
    const float* ap = X + (size_t)cr * 512 + l4 * 8;
    const int swz = (l15 & 7) << 3;

#pragma unroll
    for (int kt = 0; kt < 16; ++kt) {
        const float4 x0 = *(const float4*)(ap + kt * 32);
        const float4 x1 = *(const float4*)(ap + kt * 32 + 4);
        bf16x8 a;
        a[0]=f2bf(x0.x); a[1]=f2bf(x0.y); a[2]=f2bf(x0.z); a[3]=f2bf(x0.w);
        a[4]=f2bf(x1.x); a[5]=f2bf(x1.y); a[6]=f2bf(x1.z); a[7]=f2bf(x1.w);

#pragma unroll
        for (int f = 0; f < 4; ++f) {
            const int si = ((col0 + f * 16 + l15) * 512 + kt * 32 + l4 * 8) ^ swz;
            const bf16x8 b = *(const bf16x8*)&Bs[si];
            acc[f] = __builtin_amdgcn_mfma_f32_16x16x32_bf16(a, b, acc[f], 0, 0, 0);
        }
    }

#pragma unroll
    for (int r = 0; r < 4; ++r) {
        const int row = row0 + l4 * 4 + r;
        if (row < M) {
#pragma unroll
            for (int f = 0; f < 4; ++f)
                XW1b[(size_t)row * 128 + col0 + f * 16 + l15] = f2bf(acc[f][r]);
        }
    }
}

// ---------------- CSR build ----------------
__global__ __launch_bounds__(256) void hist_kernel(const int* __restrict__ row,
                                                   int* __restrict__ counts, int E)
{
    int e = blockIdx.x * 256 + threadIdx.x;
    if (e < E) atomicAdd(&counts[row[e]], 1);
}

__global__ __launch_bounds__(256) void scan1_kernel(const int* __restrict__ counts,
                                                    int* __restrict__ excl,
                                                    int* __restrict__ bsum, int N)
{
    __shared__ int s[256];
    const int t = threadIdx.x;
    const int i = blockIdx.x * 256 + t;
    int v = (i < N) ? counts[i] : 0;
    s[t] = v; __syncthreads();
#pragma unroll
    for (int off = 1; off < 256; off <<= 1) {
        int tmp = (t >= off) ? s[t - off] : 0;
        __syncthreads();
        s[t] += tmp;
        __syncthreads();
    }
    if (i < N) excl[i] = s[t] - v;
    if (t == 255) bsum[blockIdx.x] = s[255];
}

__global__ __launch_bounds__(256) void scan2_kernel(int* __restrict__ bsum, int NB)
{
    __shared__ int s[256];
    const int t = threadIdx.x;
    int v = (t < NB) ? bsum[t] : 0;
    s[t] = v; __syncthreads();
#pragma unroll
    for (int off = 1; off < 256; off <<= 1) {
        int tmp = (t >= off) ? s[t - off] : 0;
        __syncthreads();
        s[t] += tmp;
        __syncthreads();
    }
    if (t < NB) bsum[t] = s[t] - v;
}

__global__ __launch_bounds__(256) void scan3_kernel(int* __restrict__ rowptr,
                                                    const int* __restrict__ bsum,
                                                    int* __restrict__ cur, int N, int E)
{
    int i = blockIdx.x * 256 + threadIdx.x;
    if (i < N) {
        int v = rowptr[i] + bsum[blockIdx.x];
        rowptr[i] = v;
        cur[i] = v;
    }
    if (i == 0) rowptr[N] = E;
}

__global__ __launch_bounds__(256) void sortedges_kernel(
    const int* __restrict__ row, const int* __restrict__ col,
    const float* __restrict__ w, int* __restrict__ cur,
    int2* __restrict__ se, int E)
{
    int e = blockIdx.x * 256 + threadIdx.x;
    if (e < E) {
        int r = row[e];
        int pos = atomicAdd(&cur[r], 1);
        se[pos] = make_int2(col[e], __float_as_int(w[e]));
    }
}

// ---- segment1: hb[r] = bf16(relu(b1 + sum_j w_j * xw1b[col_j])) ----
// 2 lane-halves process 2 edges per load instr (32 lanes x 8B = one 256B row), x2 unroll.
__global__ __launch_bounds__(256) void segment1_kernel(
    const int* __restrict__ rowptr, const int2* __restrict__ se,
    const uint2* __restrict__ x2, const float* __restrict__ b1,
    uint2* __restrict__ hb, int N)
{
    const int w    = threadIdx.x >> 6;
    const int lane = threadIdx.x & 63;
    const int h    = lane >> 5;          // half: which edge of the pair
    const int q    = lane & 31;          // uint2 index in row (feats 4q..4q+3)
    const int r = blockIdx.x * 4 + w;
    if (r >= N) return;

    float4 acc = make_float4(0.f, 0.f, 0.f, 0.f);
    if (h == 0) acc = *(const float4*)(b1 + 4 * q);

    int j = rowptr[r];
    const int end = rowptr[r + 1];
    for (; j + 3 < end; j += 4) {
        const int2 ea = se[j + h];
        const int2 eb = se[j + 2 + h];
        const uint2 ua = x2[(size_t)ea.x * 32 + q];
        const uint2 ub = x2[(size_t)eb.x * 32 + q];
        const float wa = __int_as_float(ea.y), wb = __int_as_float(eb.y);
        acc.x = fmaf(wa, bflo(ua.x), acc.x); acc.y = fmaf(wa, bfhi(ua.x), acc.y);
        acc.z = fmaf(wa, bflo(ua.y), acc.z); acc.w = fmaf(wa, bfhi(ua.y), acc.w);
        acc.x = fmaf(wb, bflo(ub.x), acc.x); acc.y = fmaf(wb, bfhi(ub.x), acc.y);
        acc.z = fmaf(wb, bflo(ub.y), acc.z); acc.w = fmaf(wb, bfhi(ub.y), acc.w);
    }
    for (; j < end; j += 2) {
        const int idx = j + h;
        const int ic  = idx < end ? idx : end - 1;
        const int2 e  = se[ic];
        const float wt = idx < end ? __int_as_float(e.y) : 0.f;
        const uint2 u = x2[(size_t)e.x * 32 + q];
        acc.x = fmaf(wt, bflo(u.x), acc.x); acc.y = fmaf(wt, bfhi(u.x), acc.y);
        acc.z = fmaf(wt, bflo(u.y), acc.z); acc.w = fmaf(wt, bfhi(u.y), acc.w);
    }
    // combine halves
    acc.x += __shfl_xor(acc.x, 32);
    acc.y += __shfl_xor(acc.y, 32);
    acc.z += __shfl_xor(acc.z, 32);
    acc.w += __shfl_xor(acc.w, 32);
    if (h == 0) {
        const unsigned p0 = pack2bf(fmaxf(acc.x, 0.f), fmaxf(acc.y, 0.f));
        const unsigned p1 = pack2bf(fmaxf(acc.z, 0.f), fmaxf(acc.w, 0.f));
        hb[(size_t)r * 32 + q] = make_uint2(p0, p1);
    }
}

// ---------------- GEMM2: Yb[M,40](bf16) = hb[M,128](bf16) @ W2 ----------------
__global__ __launch_bounds__(256) void gemm2_mfma_kernel(
    const short* __restrict__ hb, const short* __restrict__ W2Ts,
    unsigned short* __restrict__ Yb, int M)
{
    __shared__ __align__(16) short Ws[48 * 128];   // 12 KB, pre-swizzled

    const int tid = threadIdx.x;
    const int w   = tid >> 6;
    const int l   = tid & 63;
    const int l15 = l & 15;
    const int l4  = l >> 4;
    const int row0 = blockIdx.x * 64 + w * 16;

    {
        const char* src = (const char*)W2Ts;
        char* dst = (char*)Ws;
#pragma unroll
        for (int i = 0; i < 3; ++i)
            gload16(src + i * 4096 + tid * 16, dst + i * 4096 + tid * 16);
    }
    __syncthreads();

    f32x4 acc[3];
#pragma unroll
    for (int f = 0; f < 3; ++f) acc[f] = (f32x4)0.f;

    const int rr = row0 + l15;
    const int cr = rr < M ? rr : M - 1;
    const short* hp = hb + (size_t)cr * 128 + l4 * 8;
    const int swz = (l15 & 7) << 3;

#pragma unroll
    for (int kt = 0; kt < 4; ++kt) {
        const bf16x8 a = *(const bf16x8*)(hp + kt * 32);
#pragma unroll
        for (int f = 0; f < 3; ++f) {
            const int si = ((f * 16 + l15) * 128 + kt * 32 + l4 * 8) ^ swz;
            const bf16x8 b = *(const bf16x8*)&Ws[si];
            acc[f] = __builtin_amdgcn_mfma_f32_16x16x32_bf16(a, b, acc[f], 0, 0, 0);
        }
    }

#pragma unroll
    for (int r = 0; r < 4; ++r) {
        const int row = row0 + l4 * 4 + r;
        if (row < M) {
#pragma unroll
            for (int f = 0; f < 3; ++f) {
                const int col = f * 16 + l15;
                if (col < 40)
                    Yb[(size_t)row * 40 + col] = (unsigned short)f2bf(acc[f][r]);
            }
        }
    }
}

// ---- segment2: out[r] = b2 + sum_j w_j * hw2b[col_j]  (3 edges/wave, x2 unroll) ----
__global__ __launch_bounds__(256) void segment2_kernel(
    const int* __restrict__ rowptr, const int2* __restrict__ se,
    const unsigned* __restrict__ hw2, const float* __restrict__ b2,
    float* __restrict__ out, int N)
{
    const int w    = threadIdx.x >> 6;
    const int lane = threadIdx.x & 63;
    const int s    = lane < 20 ? 0 : (lane < 40 ? 1 : 2);
    const int fl   = lane - s * 20;          // 0..19 (lanes 60-63 -> 20..23, discarded)
    const int r = blockIdx.x * 4 + w;
    if (r >= N) return;

    float a0 = 0.f, a1 = 0.f;
    if (lane < 20) { float2 bb = *(const float2*)(b2 + 2 * fl); a0 = bb.x; a1 = bb.y; }

    int j = rowptr[r];
    const int end = rowptr[r + 1];
    for (; j + 5 < end; j += 6) {
        const int2 ea = se[j + s];
        const int2 eb = se[j + 3 + s];
        const unsigned ua = hw2[(size_t)ea.x * 20 + fl];
        const unsigned ub = hw2[(size_t)eb.x * 20 + fl];
        const float wa = __int_as_float(ea.y), wb = __int_as_float(eb.y);
        a0 = fmaf(wa, bflo(ua), a0); a1 = fmaf(wa, bfhi(ua), a1);
        a0 = fmaf(wb, bflo(ub), a0); a1 = fmaf(wb, bfhi(ub), a1);
    }
    for (; j < end; j += 3) {
        const int idx = j + s;
        const int ic  = idx < end ? idx : end - 1;
        const int2 e  = se[ic];
        const float wt = idx < end ? __int_as_float(e.y) : 0.f;
        const unsigned u = hw2[(size_t)e.x * 20 + fl];
        a0 = fmaf(wt, bflo(u), a0); a1 = fmaf(wt, bfhi(u), a1);
    }
    const float t0 = __shfl(a0, lane + 20);
    const float t1 = __shfl(a1, lane + 20);
    const float u0 = __shfl(a0, lane + 40);
    const float u1 = __shfl(a1, lane + 40);
    if (lane < 20)
        *(float2*)(out + (size_t)r * 40 + 2 * fl) = make_float2(a0 + t0 + u0, a1 + t1 + u1);
}

extern "C" void kernel_launch(void* const* d_in, const int* in_sizes, int n_in,
                              void* d_out, int out_size, void* d_ws, size_t ws_size,
                              hipStream_t stream)
{
    const float* x  = (const float*)d_in[0];
    const int* erow = (const int*)d_in[1];
    const int* ecol = (const int*)d_in[2];
    const float* ew = (const float*)d_in[3];
    const float* w1 = (const float*)d_in[4];
    const float* b1 = (const float*)d_in[5];
    const float* w2 = (const float*)d_in[6];
    const float* b2 = (const float*)d_in[7];
    float* out = (float*)d_out;

    const int N = in_sizes[0] / 512;   // 50000
    const int E = in_sizes[1];         // 800000
    const int NB = (N + 255) / 256;    // 196 (<=256 for scan2)

    // workspace layout (16B-aligned segments)
    short* w1ts = (short*)d_ws;                      // 128*512 bf16 (swizzled)
    short* w2ts = w1ts + 65536;                      // 48*128 bf16 (swizzled, +pad)
    short* xw1b = w2ts + 8192;                       // N*128 bf16
    short* hb   = xw1b + (size_t)N * 128;            // N*128 bf16 (relu'd)
    int* rowptr = (int*)(hb + (size_t)N * 128);      // N+1
    int* cur    = rowptr + (N + 1);                  // N
    int* bsum   = cur + N;                           // 256 (+pad to 8B align)
    int2* se    = (int2*)(bsum + 256 + ((N + 1) & 1)); // E packed edges
    short* hw2b = xw1b;                              // N*40 bf16 (reuse)

    // prep (weights + zero cur) and CSR build
    prep_kernel<<<(65536 + 6144 + N + 255) / 256, 256, 0, stream>>>(w1, w1ts, w2, w2ts, cur, N);
    hist_kernel<<<(E + 255) / 256, 256, 0, stream>>>(erow, cur, E);
    scan1_kernel<<<NB, 256, 0, stream>>>(cur, rowptr, bsum, N);
    scan2_kernel<<<1, 256, 0, stream>>>(bsum, NB);
    scan3_kernel<<<NB, 256, 0, stream>>>(rowptr, bsum, cur, N, E);
    sortedges_kernel<<<(E + 255) / 256, 256, 0, stream>>>(erow, ecol, ew, cur, se, E);

    // layer 1
    gemm1_mfma_kernel<<<(N + 127) / 128, 1024, 0, stream>>>(x, w1ts, xw1b, N);
    segment1_kernel<<<(N + 3) / 4, 256, 0, stream>>>(rowptr, se,
                                                     (const uint2*)xw1b, b1,
                                                     (uint2*)hb, N);

    // layer 2
    gemm2_mfma_kernel<<<(N + 63) / 64, 256, 0, stream>>>(hb, w2ts,
                                                         (unsigned short*)hw2b, N);
    segment2_kernel<<<(N + 3) / 4, 256, 0, stream>>>(rowptr, se,
                                                     (const unsigned*)hw2b, b2, out, N);
}